// Round 2
// baseline (296.269 us; speedup 1.0000x reference)
//
#include <hip/hip_runtime.h>
#include <hip/hip_bf16.h>

#define NN 32768   // nodes
#define BB 64      // graphs
#define MM 512     // nodes per graph
#define HH 4       // heads
#define DD 64      // head dim
#define INF 256    // input features
#define HD 256     // H*D
#define EE 524288  // edges

typedef unsigned short ushort;
typedef unsigned int uint;
typedef short s16x8 __attribute__((ext_vector_type(8)));
typedef ushort u16x8 __attribute__((ext_vector_type(8)));
typedef float f32x4 __attribute__((ext_vector_type(4)));

__device__ __forceinline__ ushort f2bf(float f) {
    uint u = __float_as_uint(f);
    return (ushort)((u + 0x7fffu + ((u >> 16) & 1u)) >> 16);
}
__device__ __forceinline__ float bf2f(ushort u) {
    return __uint_as_float((uint)u << 16);
}
__device__ __forceinline__ uint pkbf(float x, float y) {
    __hip_bfloat162 h = __float22bfloat162_rn(make_float2(x, y));
    return *(uint*)&h;
}

// ---------------------------------------------------------------------------
// K1: convert_w (blocks 0..767) ∪ deg histogram (blocks 768..2815).
// ---------------------------------------------------------------------------
__global__ __launch_bounds__(256) void prep_kernel(
    const float* __restrict__ Wq, const float* __restrict__ Wk,
    const float* __restrict__ Wv, ushort* __restrict__ WT,
    const int* __restrict__ ei, int* __restrict__ deg)
{
    const int bid = blockIdx.x;
    if (bid < 768) {
        const int id = bid * 256 + threadIdx.x;      // 3*65536
        const int mat = id >> 16, rem = id & 65535;
        const int n = rem >> 8, kk = rem & 255;
        const float* W = (mat == 0) ? Wq : (mat == 1) ? Wk : Wv;
        WT[id] = f2bf(W[kk * 256 + n]);              // WT[mat][n][kk]
    } else {
        const int e = (bid - 768) * 256 + threadIdx.x;   // EE total
        atomicAdd(&deg[ei[EE + e]], 1);
    }
}

// ---------------------------------------------------------------------------
// K2: qkv GEMM (blocks 0..1535) ∪ scan (block 1536).
// Barrier-free K-loop: A f32 fragments global->reg + v_cvt_pk_bf16_f32;
// B bf16 fragments global->reg (L2-resident 64KB panel). No LDS, no
// __syncthreads, no bank conflicts; all offsets compile-time immediates.
// ---------------------------------------------------------------------------
__global__ __launch_bounds__(256) void qkv_scan(
    const float* __restrict__ Xq, const float* __restrict__ Xs,
    const ushort* __restrict__ WT,
    const float* __restrict__ bq, const float* __restrict__ bk,
    const float* __restrict__ bv,
    ushort* __restrict__ qo, ushort* __restrict__ ko, ushort* __restrict__ vo,
    float* __restrict__ sumsq,
    const int* __restrict__ deg, int* __restrict__ offsets)
{
    __shared__ float wred[4];
    __shared__ int part[256];

    const int id = blockIdx.x;
    const int t = threadIdx.x;

    if (id == 1536) {   // exclusive scan of deg -> offsets, 128 elems/thread
        const int base = t * 128;
        int s = 0;
        for (int i = 0; i < 128; ++i) s += deg[base + i];
        part[t] = s;
        __syncthreads();
        for (int off = 1; off < 256; off <<= 1) {
            int a = part[t];
            int b2 = (t >= off) ? part[t - off] : 0;
            __syncthreads();
            part[t] = a + b2;
            __syncthreads();
        }
        int run = (t == 0) ? 0 : part[t - 1];
        for (int i = 0; i < 128; ++i) { offsets[base + i] = run; run += deg[base + i]; }
        if (t == 255) offsets[NN] = run;
        return;
    }

    const int vv = (id & 7) * 192 + (id >> 3);   // XCD-contiguous row-groups
    const int rt = vv / 6, ct = vv % 6;
    const int wsel = ct >> 1;                    // 0:q 1:k 2:v
    const float* A    = (wsel == 0) ? Xq : Xs;
    const ushort* W   = WT + (size_t)wsel * 65536;
    const float* bias = (wsel == 0) ? bq : (wsel == 1) ? bk : bv;
    ushort* C         = (wsel == 0) ? qo : (wsel == 1) ? ko : vo;
    const int row0 = rt * 128;
    const int col0 = (ct & 1) * 128;

    const int l = t & 63, w = t >> 6;
    const int fr = l & 15, q4 = l >> 4;
    const int wr = (w & 1) * 64, wc = (w >> 1) * 64;

    f32x4 acc[4][4] = {};

    // per-lane fragment base pointers (K-offset folds into imm offsets)
    const float* ap[4];
    const ushort* bp[4];
#pragma unroll
    for (int i = 0; i < 4; ++i)
        ap[i] = A + (size_t)(row0 + wr + i * 16 + fr) * INF + q4 * 8;
#pragma unroll
    for (int j = 0; j < 4; ++j)
        bp[j] = W + (size_t)(col0 + wc + j * 16 + fr) * INF + q4 * 8;

#pragma unroll
    for (int it = 0; it < 8; ++it) {
        s16x8 af[4], bfr[4];
#pragma unroll
        for (int j = 0; j < 4; ++j)
            bfr[j] = *(const s16x8*)(bp[j] + it * 32);
#pragma unroll
        for (int i = 0; i < 4; ++i) {
            const float4 lo = *(const float4*)(ap[i] + it * 32);
            const float4 hi = *(const float4*)(ap[i] + it * 32 + 4);
            union { s16x8 v; uint u[4]; } cv;
            cv.u[0] = pkbf(lo.x, lo.y);
            cv.u[1] = pkbf(lo.z, lo.w);
            cv.u[2] = pkbf(hi.x, hi.y);
            cv.u[3] = pkbf(hi.z, hi.w);
            af[i] = cv.v;
        }
#pragma unroll
        for (int i = 0; i < 4; ++i)
#pragma unroll
            for (int j = 0; j < 4; ++j)
                acc[i][j] = __builtin_amdgcn_mfma_f32_16x16x32_bf16(
                    af[i], bfr[j], acc[i][j], 0, 0, 0);
    }

    float loc = 0.f;
#pragma unroll
    for (int j = 0; j < 4; ++j) {
        const int colg = col0 + wc + j * 16 + fr;
        const float bj = bias[colg];
#pragma unroll
        for (int i = 0; i < 4; ++i) {
            const int rowg = row0 + wr + i * 16 + q4 * 4;
#pragma unroll
            for (int m = 0; m < 4; ++m) {
                float cv = acc[i][j][m] + bj;
                loc += cv * cv;
                C[(size_t)(rowg + m) * HD + colg] = f2bf(cv);
            }
        }
    }
    if (wsel < 2) {
#pragma unroll
        for (int off = 32; off > 0; off >>= 1) loc += __shfl_down(loc, off, 64);
        if (l == 0) wred[w] = loc;
        __syncthreads();
        if (t == 0) atomicAdd(&sumsq[wsel], wred[0] + wred[1] + wred[2] + wred[3]);
    }
}

// ---------------------------------------------------------------------------
// K3: kv_mfma (blocks 0..1023) ∪ vbar (blocks 1024..3071, 4 elems/thread).
// kv parts stored transposed [dv][dk] for attn's B-operand layout.
// ---------------------------------------------------------------------------
#define KVP 136
__global__ __launch_bounds__(256) void kv_vbar(
    const ushort* __restrict__ k16, const ushort* __restrict__ v16,
    float* __restrict__ kv_p, float* __restrict__ ksum_p, float* __restrict__ vsum_p,
    float* __restrict__ vbar)
{
    __shared__ ushort kT[64 * KVP];
    __shared__ ushort vT[64 * KVP];
    const int bid = blockIdx.x;
    const int t = threadIdx.x;

    if (bid >= 1024) {   // vbar: mean over heads
        const int idx = (bid - 1024) * 1024 + t * 4;
        const int n = idx >> 6, d0 = idx & 63;
        const ushort* vr = &v16[(size_t)n * HD + d0];
        float4 o;
        float* op = (float*)&o;
#pragma unroll
        for (int j = 0; j < 4; ++j)
            op[j] = 0.25f * (bf2f(vr[j]) + bf2f(vr[64 + j]) +
                             bf2f(vr[128 + j]) + bf2f(vr[192 + j]));
        *(float4*)&vbar[idx] = o;
        return;
    }

    const int h = bid & 3, b = (bid >> 2) & 63, z = bid >> 8;
    const int l = t & 63, w = t >> 6;
    const size_t base = (size_t)b * MM * HD + (size_t)h * DD;
    const int m0 = z * 128;

    {
        const int mat = t >> 7;
        const int u = t & 63;
        const int dhalf = (t >> 6) & 1;
        const int r0 = 2 * u;
        const int d0 = dhalf * 32;
        const ushort* src = mat ? v16 : k16;
        ushort* dst = mat ? vT : kT;
        const ushort* p0 = &src[base + (size_t)(m0 + r0) * HD + d0];
        const ushort* p1 = p0 + HD;
        u16x8 ra[4], rb[4];
#pragma unroll
        for (int i = 0; i < 4; ++i) ra[i] = *(const u16x8*)(p0 + 8 * i);
#pragma unroll
        for (int i = 0; i < 4; ++i) rb[i] = *(const u16x8*)(p1 + 8 * i);
#pragma unroll
        for (int i = 0; i < 4; ++i)
#pragma unroll
            for (int jj = 0; jj < 8; ++jj) {
                const int d = d0 + 8 * i + jj;
                uint pk = (uint)ra[i][jj] | ((uint)rb[i][jj] << 16);
                *(uint*)&dst[d * KVP + r0] = pk;
            }
    }
    __syncthreads();

    const int fr = l & 15, q4 = l >> 4, kg = q4 * 8;
    const int wr2 = (w & 1) * 32, wc2 = (w >> 1) * 32;
    s16x8 ones;
#pragma unroll
    for (int i = 0; i < 8; ++i) ones[i] = (short)0x3F80;

    f32x4 acc[2][2] = {};
    f32x4 aks[2] = {};
    f32x4 avs[2] = {};
#pragma unroll
    for (int s = 0; s < 4; ++s) {
        const int mo = s * 32 + kg;
        s16x8 af[2], bf[2];
        af[0] = *(const s16x8*)&kT[(wr2 + fr) * KVP + mo];
        af[1] = *(const s16x8*)&kT[(wr2 + 16 + fr) * KVP + mo];
        bf[0] = *(const s16x8*)&vT[(wc2 + fr) * KVP + mo];
        bf[1] = *(const s16x8*)&vT[(wc2 + 16 + fr) * KVP + mo];
#pragma unroll
        for (int il = 0; il < 2; ++il)
#pragma unroll
            for (int jl = 0; jl < 2; ++jl)
                acc[il][jl] = __builtin_amdgcn_mfma_f32_16x16x32_bf16(
                    af[il], bf[jl], acc[il][jl], 0, 0, 0);
#pragma unroll
        for (int il = 0; il < 2; ++il)
            aks[il] = __builtin_amdgcn_mfma_f32_16x16x32_bf16(
                af[il], ones, aks[il], 0, 0, 0);
#pragma unroll
        for (int jl = 0; jl < 2; ++jl)
            avs[jl] = __builtin_amdgcn_mfma_f32_16x16x32_bf16(
                ones, bf[jl], avs[jl], 0, 0, 0);
    }

    float* kvb = &kv_p[(((size_t)b * HH + h) * 4 + z) * 4096];
#pragma unroll
    for (int jl = 0; jl < 2; ++jl) {
        const int dv = wc2 + 16 * jl + fr;
#pragma unroll
        for (int il = 0; il < 2; ++il) {
            const int dk = wr2 + 16 * il + q4 * 4;
            *(f32x4*)&kvb[(size_t)dv * 64 + dk] = acc[il][jl];
        }
    }
    float* ksb = &ksum_p[(((size_t)b * HH + h) * 4 + z) * 64];
    float* vsb = &vsum_p[(((size_t)b * HH + h) * 4 + z) * 64];
    if (wc2 == 0 && fr == 0) {
#pragma unroll
        for (int il = 0; il < 2; ++il)
#pragma unroll
            for (int m = 0; m < 4; ++m)
                ksb[wr2 + 16 * il + q4 * 4 + m] = aks[il][m];
    }
    if (wr2 == 0 && l < 16) {
        vsb[wc2 + l]      = avs[0][0];
        vsb[wc2 + 16 + l] = avs[1][0];
    }
}

// ---------------------------------------------------------------------------
// K4: kv_red (blocks 0..1023) ∪ sumred (1024..1151) ∪ bucket (1152..3199).
// ---------------------------------------------------------------------------
__global__ __launch_bounds__(256) void red_bucket(
    const float* __restrict__ kv_p, const float* __restrict__ ksum_p,
    const float* __restrict__ vsum_p,
    ushort* __restrict__ kv16, float* __restrict__ ksum_f, float* __restrict__ vsum_f,
    const int* __restrict__ ei, const float* __restrict__ ew,
    const int* __restrict__ deg, const int* __restrict__ offsets,
    int* __restrict__ cursor, int2* __restrict__ pairbuf)
{
    const int bid = blockIdx.x;
    const int t = threadIdx.x;

    if (bid < 1024) {          // kv_red: 4 outputs/thread
        const int o4 = bid * 1024 + t * 4;
        const int bh = o4 >> 12, off = o4 & 4095;
        const float* p = &kv_p[(size_t)bh * 16384 + off];
        float4 s0 = *(const float4*)p;
        float4 s1 = *(const float4*)(p + 4096);
        float4 s2 = *(const float4*)(p + 8192);
        float4 s3 = *(const float4*)(p + 12288);
        const float r0 = s0.x + s1.x + s2.x + s3.x;
        const float r1 = s0.y + s1.y + s2.y + s3.y;
        const float r2 = s0.z + s1.z + s2.z + s3.z;
        const float r3 = s0.w + s1.w + s2.w + s3.w;
        uint2 pk = make_uint2(pkbf(r0, r1), pkbf(r2, r3));
        *(uint2*)&kv16[(size_t)bh * 4096 + off] = pk;
    } else if (bid < 1152) {   // ksum/vsum reduce
        const int o = (bid - 1024) * 256 + t;    // 0..32767
        const float* src = (o < 16384) ? ksum_p : vsum_p;
        float* dst = (o < 16384) ? ksum_f : vsum_f;
        const int oo = o & 16383;
        const int bh = oo >> 6, d = oo & 63;
        const float* p = &src[(size_t)bh * 256 + d];
        dst[oo] = p[0] + p[64] + p[128] + p[192];
    } else {                   // bucket
        const int e = (bid - 1152) * 256 + t;
        const int row = ei[e], col = ei[EE + e];
        const long long prod = (long long)deg[row] * (long long)deg[col];
        float val = 0.f;
        if (prod > 0) val = ew[e] * __frsqrt_rn((float)prod);
        const int pos = atomicAdd(&cursor[col], 1);
        pairbuf[offsets[col] + pos] = make_int2(row, __float_as_int(val));
    }
}

// ---------------------------------------------------------------------------
// K5: attn via MFMA. P = q[64x64] x KV^T; KV staged bf16 from kv16.
// ---------------------------------------------------------------------------
#define AKP 72
__global__ __launch_bounds__(256) void attn_mfma(
    const ushort* __restrict__ q16, const ushort* __restrict__ kv16,
    const float* __restrict__ ksum_f, const float* __restrict__ vsum_f,
    const float* __restrict__ sumsq,
    const int* __restrict__ n_nodes, float* __restrict__ out)
{
    const int b = blockIdx.y;
    const int m0 = blockIdx.x * 64;
    const int t = threadIdx.x;
    const int l = t & 63, w = t >> 6;
    const int fr = l & 15, q4 = l >> 4;
    const int wn = (w & 1) * 32, wd = (w >> 1) * 32;

    __shared__ ushort kvbf[64 * AKP];
    __shared__ float ksum_l[64], vsum_l[64], denom_l[64];

    const float nn = (float)n_nodes[b];
    const float inv = 1.0f / (sqrtf(sumsq[0]) * sqrtf(sumsq[1]));
    f32x4 acco[2][2] = {};

    for (int h = 0; h < HH; ++h) {
        __syncthreads();
        {   // stage bf16 KV [dv][dk]
            const int dv = t >> 2, dk0 = (t & 3) * 16;
            const ushort* kvg = &kv16[((size_t)(b * HH + h)) * 4096 + dv * 64 + dk0];
            *(uint4*)&kvbf[dv * AKP + dk0]     = *(const uint4*)kvg;
            *(uint4*)&kvbf[dv * AKP + dk0 + 8] = *(const uint4*)(kvg + 8);
        }
        if (t >= 64 && t < 128)
            ksum_l[t - 64] = ksum_f[((size_t)(b * HH + h)) * 64 + t - 64];
        else if (t >= 128 && t < 192)
            vsum_l[t - 128] = vsum_f[((size_t)(b * HH + h)) * 64 + t - 128];
        __syncthreads();

        if (t < 64) {   // denominators
            const ushort* qr = &q16[((size_t)(b * MM + m0 + t)) * HD + h * DD];
            float dsum = 0.f;
#pragma unroll
            for (int c = 0; c < 8; ++c) {
                u16x8 qq = *(const u16x8*)(qr + 8 * c);
#pragma unroll
                for (int j2 = 0; j2 < 8; ++j2)
                    dsum += bf2f(qq[j2]) * ksum_l[8 * c + j2];
            }
            denom_l[t] = nn + inv * dsum;
        }
        __syncthreads();

        f32x4 pacc[2][2] = {};
#pragma unroll
        for (int kx = 0; kx < 2; ++kx) {
            const int k0 = kx * 32;
            s16x8 af[2], bf[2];
#pragma unroll
            for (int il = 0; il < 2; ++il)
                af[il] = *(const s16x8*)&q16[
                    ((size_t)(b * MM + m0 + wn + 16 * il + fr)) * HD + h * DD + k0 + q4 * 8];
#pragma unroll
            for (int jl = 0; jl < 2; ++jl)
                bf[jl] = *(const s16x8*)&kvbf[(wd + 16 * jl + fr) * AKP + k0 + q4 * 8];
#pragma unroll
            for (int il = 0; il < 2; ++il)
#pragma unroll
                for (int jl = 0; jl < 2; ++jl)
                    pacc[il][jl] = __builtin_amdgcn_mfma_f32_16x16x32_bf16(
                        af[il], bf[jl], pacc[il][jl], 0, 0, 0);
        }
#pragma unroll
        for (int il = 0; il < 2; ++il)
#pragma unroll
            for (int m = 0; m < 4; ++m) {
                const float rden = 0.25f / denom_l[wn + 16 * il + q4 * 4 + m];
#pragma unroll
                for (int jl = 0; jl < 2; ++jl) {
                    const int d = wd + 16 * jl + fr;
                    acco[il][jl][m] += (inv * pacc[il][jl][m] + vsum_l[d]) * rden;
                }
            }
    }

#pragma unroll
    for (int il = 0; il < 2; ++il)
#pragma unroll
        for (int m = 0; m < 4; ++m) {
            const size_t node = (size_t)b * MM + m0 + wn + 16 * il + q4 * 4 + m;
#pragma unroll
            for (int jl = 0; jl < 2; ++jl)
                out[node * DD + wd + 16 * jl + fr] = acco[il][jl][m];
        }
}

// ---------------------------------------------------------------------------
// K6: GCN gather (packed pairbuf), float4 per thread: 16 threads/node.
// ---------------------------------------------------------------------------
__global__ __launch_bounds__(256) void gcn_gather(
    const int* __restrict__ offsets, const int2* __restrict__ pairbuf,
    const float* __restrict__ vbar, float* __restrict__ out)
{
    const int t = blockIdx.x * 256 + threadIdx.x;   // NN*16 threads
    const int n = t >> 4, d4 = (t & 15) << 2;
    const int s = offsets[n], e = offsets[n + 1];
    float ax = 0.f, ay = 0.f, az = 0.f, aw = 0.f;
    int i = s;
    for (; i + 2 <= e; i += 2) {
        const int2 p0 = pairbuf[i], p1 = pairbuf[i + 1];
        const float w0 = __int_as_float(p0.y), w1 = __int_as_float(p1.y);
        const float4 v0 = *(const float4*)&vbar[(size_t)p0.x * DD + d4];
        const float4 v1 = *(const float4*)&vbar[(size_t)p1.x * DD + d4];
        ax += w0 * v0.x + w1 * v1.x;
        ay += w0 * v0.y + w1 * v1.y;
        az += w0 * v0.z + w1 * v1.z;
        aw += w0 * v0.w + w1 * v1.w;
    }
    if (i < e) {
        const int2 p = pairbuf[i];
        const float wv = __int_as_float(p.y);
        const float4 v = *(const float4*)&vbar[(size_t)p.x * DD + d4];
        ax += wv * v.x; ay += wv * v.y; az += wv * v.z; aw += wv * v.w;
    }
    float4 o = *(float4*)&out[(size_t)n * DD + d4];
    o.x += ax; o.y += ay; o.z += az; o.w += aw;
    *(float4*)&out[(size_t)n * DD + d4] = o;
}

// ---------------------------------------------------------------------------
extern "C" void kernel_launch(void* const* d_in, const int* in_sizes, int n_in,
                              void* d_out, int out_size, void* d_ws, size_t ws_size,
                              hipStream_t stream)
{
    (void)in_sizes; (void)n_in; (void)out_size; (void)ws_size;
    const float* Xq = (const float*)d_in[0];
    const float* Xs = (const float*)d_in[1];
    const float* ew = (const float*)d_in[2];
    const float* Wq = (const float*)d_in[3];
    const float* bq = (const float*)d_in[4];
    const float* Wk = (const float*)d_in[5];
    const float* bk = (const float*)d_in[6];
    const float* Wv = (const float*)d_in[7];
    const float* bv = (const float*)d_in[8];
    const int* n_nodes = (const int*)d_in[9];
    const int* ei = (const int*)d_in[10];
    float* out = (float*)d_out;
    float* ws  = (float*)d_ws;

    // workspace layout (float units); q/k/v bf16
    const size_t SZ_QKV   = (size_t)NN * HD / 2;       // 4194304 each
    const size_t OFF_Q    = 0;
    const size_t OFF_K    = SZ_QKV;
    const size_t OFF_V    = SZ_QKV * 2;
    const size_t OFF_SS   = SZ_QKV * 3;                // 16 floats (zeroed)
    const size_t OFF_DEG  = OFF_SS + 16;               // NN ints (zeroed)
    const size_t OFF_CUR  = OFF_DEG + NN;              // NN ints (zeroed)
    const size_t OFF_WT   = OFF_CUR + NN;              // 3*65536 ushorts
    const size_t OFF_OFFS = OFF_WT + 3 * 65536 / 2;    // NN+1 (+pad)
    const size_t OFF_KV   = OFF_OFFS + NN + 16;                       // 4194304
    const size_t OFF_KSP  = OFF_KV + (size_t)BB * HH * 4 * 4096;      // 65536
    const size_t OFF_VSP  = OFF_KSP + (size_t)BB * HH * 4 * 64;       // 65536
    const size_t OFF_KV16 = OFF_VSP + (size_t)BB * HH * 4 * 64;       // 524288
    const size_t OFF_KSF  = OFF_KV16 + (size_t)BB * HH * 4096 / 2;    // 16384
    const size_t OFF_VSF  = OFF_KSF + (size_t)BB * HH * 64;           // 16384
    const size_t OFF_PAIR = OFF_VSF + (size_t)BB * HH * 64;           // 1048576
    const size_t OFF_VBAR = OFF_PAIR + 2 * (size_t)EE;                // 2097152
    // total ≈ 82 MB

    ushort* q16   = (ushort*)(ws + OFF_Q);
    ushort* k16   = (ushort*)(ws + OFF_K);
    ushort* v16   = (ushort*)(ws + OFF_V);
    float* sumsq  = ws + OFF_SS;
    int*   deg    = (int*)(ws + OFF_DEG);
    int*   cursor = (int*)(ws + OFF_CUR);
    ushort* WT    = (ushort*)(ws + OFF_WT);
    int*   offs   = (int*)(ws + OFF_OFFS);
    float* kv_p   = ws + OFF_KV;
    float* ksum_p = ws + OFF_KSP;
    float* vsum_p = ws + OFF_VSP;
    ushort* kv16  = (ushort*)(ws + OFF_KV16);
    float* ksum_f = ws + OFF_KSF;
    float* vsum_f = ws + OFF_VSF;
    int2*  pairb  = (int2*)(ws + OFF_PAIR);
    float* vbar   = ws + OFF_VBAR;

    // zero sumsq + deg + cursor (contiguous)
    hipMemsetAsync(sumsq, 0, (16 + 2 * NN) * sizeof(float), stream);
    prep_kernel<<<2816, 256, 0, stream>>>(Wq, Wk, Wv, WT, ei, deg);
    qkv_scan<<<1537, 256, 0, stream>>>(
        Xq, Xs, WT, bq, bk, bv, q16, k16, v16, sumsq, deg, offs);
    kv_vbar<<<3072, 256, 0, stream>>>(k16, v16, kv_p, ksum_p, vsum_p, vbar);
    red_bucket<<<3200, 256, 0, stream>>>(
        kv_p, ksum_p, vsum_p, kv16, ksum_f, vsum_f,
        ei, ew, deg, offs, cursor, pairb);
    attn_mfma<<<dim3(MM / 64, BB), 256, 0, stream>>>(
        q16, kv16, ksum_f, vsum_f, sumsq, n_nodes, out);
    gcn_gather<<<(NN * 16) / 256, 256, 0, stream>>>(offs, pairb, vbar, out);
}

// Round 3
// 284.112 us; speedup vs baseline: 1.0428x; 1.0428x over previous
//
#include <hip/hip_runtime.h>
#include <hip/hip_bf16.h>

#define NN 32768   // nodes
#define BB 64      // graphs
#define MM 512     // nodes per graph
#define HH 4       // heads
#define DD 64      // head dim
#define INF 256    // input features
#define HD 256     // H*D
#define EE 524288  // edges
#define XSZ 8388608  // NN*INF elements per X matrix

typedef unsigned short ushort;
typedef unsigned int uint;
typedef short s16x8 __attribute__((ext_vector_type(8)));
typedef ushort u16x8 __attribute__((ext_vector_type(8)));
typedef float f32x4 __attribute__((ext_vector_type(4)));

__device__ __forceinline__ ushort f2bf(float f) {
    uint u = __float_as_uint(f);
    return (ushort)((u + 0x7fffu + ((u >> 16) & 1u)) >> 16);
}
__device__ __forceinline__ float bf2f(ushort u) {
    return __uint_as_float((uint)u << 16);
}
__device__ __forceinline__ uint pkbf(float x, float y) {
    __hip_bfloat162 h = __float22bfloat162_rn(make_float2(x, y));
    return *(uint*)&h;
}

#define GLD16(gp, lp) __builtin_amdgcn_global_load_lds( \
    (const __attribute__((address_space(1))) void*)(gp), \
    (__attribute__((address_space(3))) void*)(lp), 16, 0, 0)

// ---------------------------------------------------------------------------
// K1: convert_w (blocks 0..767) ∪ deg histogram (blocks 768..2815) ∪
//     X f32->bf16 convert (blocks 2816..11007).
// ---------------------------------------------------------------------------
__global__ __launch_bounds__(256) void prep_kernel(
    const float* __restrict__ Wq, const float* __restrict__ Wk,
    const float* __restrict__ Wv, ushort* __restrict__ WT,
    const int* __restrict__ ei, int* __restrict__ deg,
    const float* __restrict__ Xq, const float* __restrict__ Xs,
    ushort* __restrict__ xq16, ushort* __restrict__ xs16)
{
    const int bid = blockIdx.x;
    if (bid < 768) {
        const int id = bid * 256 + threadIdx.x;      // 3*65536
        const int mat = id >> 16, rem = id & 65535;
        const int n = rem >> 8, kk = rem & 255;
        const float* W = (mat == 0) ? Wq : (mat == 1) ? Wk : Wv;
        WT[id] = f2bf(W[kk * 256 + n]);              // WT[mat][n][kk]
    } else if (bid < 2816) {
        const int e = (bid - 768) * 256 + threadIdx.x;   // EE total
        atomicAdd(&deg[ei[EE + e]], 1);
    } else {
        const size_t id = (size_t)(bid - 2816) * 256 + threadIdx.x;
        const size_t o8 = id * 8;                    // 8 floats / thread
        const float* src; ushort* dst; size_t o;
        if (o8 < XSZ) { src = Xq; dst = xq16; o = o8; }
        else          { src = Xs; dst = xs16; o = o8 - XSZ; }
        const float4 f0 = *(const float4*)(src + o);
        const float4 f1 = *(const float4*)(src + o + 4);
        u16x8 r;
        r[0] = f2bf(f0.x); r[1] = f2bf(f0.y); r[2] = f2bf(f0.z); r[3] = f2bf(f0.w);
        r[4] = f2bf(f1.x); r[5] = f2bf(f1.y); r[6] = f2bf(f1.z); r[7] = f2bf(f1.w);
        *(u16x8*)(dst + o) = r;
    }
}

// ---------------------------------------------------------------------------
// K2: qkv GEMM (blocks 0..1535) ∪ scan (block 1536). Round-1 structure
// (measured 46us): global_load_lds width=16 into linear [128][32] LDS,
// double-buffered, one barrier per K-step.
// ---------------------------------------------------------------------------
__global__ __launch_bounds__(256) void qkv_scan(
    const ushort* __restrict__ Xq16, const ushort* __restrict__ Xs16,
    const ushort* __restrict__ WT,
    const float* __restrict__ bq, const float* __restrict__ bk,
    const float* __restrict__ bv,
    ushort* __restrict__ qo, ushort* __restrict__ ko, ushort* __restrict__ vo,
    float* __restrict__ sumsq,
    const int* __restrict__ deg, int* __restrict__ offsets)
{
    __shared__ ushort As[2][128 * 32];
    __shared__ ushort Bs[2][128 * 32];
    __shared__ float wred[4];
    __shared__ int part[256];

    const int id = blockIdx.x;
    const int t = threadIdx.x;

    if (id == 1536) {   // exclusive scan of deg -> offsets, 128 elems/thread
        const int base = t * 128;
        int s = 0;
        for (int i = 0; i < 128; ++i) s += deg[base + i];
        part[t] = s;
        __syncthreads();
        for (int off = 1; off < 256; off <<= 1) {
            int a = part[t];
            int b2 = (t >= off) ? part[t - off] : 0;
            __syncthreads();
            part[t] = a + b2;
            __syncthreads();
        }
        int run = (t == 0) ? 0 : part[t - 1];
        for (int i = 0; i < 128; ++i) { offsets[base + i] = run; run += deg[base + i]; }
        if (t == 255) offsets[NN] = run;
        return;
    }

    const int vv = (id & 7) * 192 + (id >> 3);   // XCD-contiguous row-groups
    const int rt = vv / 6, ct = vv % 6;
    const int wsel = ct >> 1;                    // 0:q 1:k 2:v
    const ushort* A16 = (wsel == 0) ? Xq16 : Xs16;
    const ushort* W   = WT + (size_t)wsel * 65536;
    const float* bias = (wsel == 0) ? bq : (wsel == 1) ? bk : bv;
    ushort* C         = (wsel == 0) ? qo : (wsel == 1) ? ko : vo;
    const int row0 = rt * 128;
    const int col0 = (ct & 1) * 128;

    const int l = t & 63, w = t >> 6;
    const int fr = l & 15, q4 = l >> 4;
    const int wr = (w & 1) * 64, wc = (w >> 1) * 64;

    // staging: per wave, 64 lanes x 16B contiguous LDS
    const int srow = (w << 4) + (l >> 2);        // 0..63 within 64-row half
    const int scol = (l & 3) << 3;               // 0,8,16,24
    const ushort* ga = &A16[(size_t)(row0 + srow) * INF + scol];
    const ushort* gb = &W  [(size_t)(col0 + srow) * INF + scol];
    const int lbase = (w << 9);                  // wave-uniform ushort offset

    f32x4 acc[4][4] = {};

    // prologue: stage K-step 0 into buffer 0
    GLD16(ga,             &As[0][lbase]);
    GLD16(ga + 64 * INF,  &As[0][2048 + lbase]);
    GLD16(gb,             &Bs[0][lbase]);
    GLD16(gb + 64 * INF,  &Bs[0][2048 + lbase]);

    int cur = 0;
    for (int it = 0; it < 8; ++it) {
        __syncthreads();       // drains vmcnt: buf[cur] staged; prior reads done
        if (it < 7) {
            const int k0 = (it + 1) * 32;
            GLD16(ga + k0,            &As[cur ^ 1][lbase]);
            GLD16(ga + k0 + 64 * INF, &As[cur ^ 1][2048 + lbase]);
            GLD16(gb + k0,            &Bs[cur ^ 1][lbase]);
            GLD16(gb + k0 + 64 * INF, &Bs[cur ^ 1][2048 + lbase]);
        }
        const int kg = q4 * 8;
        s16x8 af[4], bfr[4];
#pragma unroll
        for (int i = 0; i < 4; ++i)
            af[i] = *(const s16x8*)&As[cur][(wr + i * 16 + fr) * 32 + kg];
#pragma unroll
        for (int j = 0; j < 4; ++j)
            bfr[j] = *(const s16x8*)&Bs[cur][(wc + j * 16 + fr) * 32 + kg];
#pragma unroll
        for (int i = 0; i < 4; ++i)
#pragma unroll
            for (int j = 0; j < 4; ++j)
                acc[i][j] = __builtin_amdgcn_mfma_f32_16x16x32_bf16(
                    af[i], bfr[j], acc[i][j], 0, 0, 0);
        cur ^= 1;
    }

    float loc = 0.f;
#pragma unroll
    for (int j = 0; j < 4; ++j) {
        const int colg = col0 + wc + j * 16 + fr;
        const float bj = bias[colg];
#pragma unroll
        for (int i = 0; i < 4; ++i) {
            const int rowg = row0 + wr + i * 16 + q4 * 4;
#pragma unroll
            for (int m = 0; m < 4; ++m) {
                float cv = acc[i][j][m] + bj;
                loc += cv * cv;
                C[(size_t)(rowg + m) * HD + colg] = f2bf(cv);
            }
        }
    }
    if (wsel < 2) {
#pragma unroll
        for (int off = 32; off > 0; off >>= 1) loc += __shfl_down(loc, off, 64);
        if (l == 0) wred[w] = loc;
        __syncthreads();
        if (t == 0) atomicAdd(&sumsq[wsel], wred[0] + wred[1] + wred[2] + wred[3]);
    }
}

// ---------------------------------------------------------------------------
// K3: kv_mfma (blocks 0..1023) ∪ vbar (1024..3071) ∪ bucket (3072..5119).
// bucket overlaps kv's MFMA phase (both depend only on qkv_scan).
// ---------------------------------------------------------------------------
#define KVP 136
__global__ __launch_bounds__(256) void kv_vbar_bucket(
    const ushort* __restrict__ k16, const ushort* __restrict__ v16,
    float* __restrict__ kv_p, float* __restrict__ ksum_p, float* __restrict__ vsum_p,
    float* __restrict__ vbar,
    const int* __restrict__ ei, const float* __restrict__ ew,
    const int* __restrict__ deg, const int* __restrict__ offsets,
    int* __restrict__ cursor, int2* __restrict__ pairbuf)
{
    __shared__ ushort kT[64 * KVP];
    __shared__ ushort vT[64 * KVP];
    const int bid = blockIdx.x;
    const int t = threadIdx.x;

    if (bid >= 3072) {   // bucket: CSR fill, packed int2 {row, val}
        const int e = (bid - 3072) * 256 + t;
        const int row = ei[e], col = ei[EE + e];
        const long long prod = (long long)deg[row] * (long long)deg[col];
        float val = 0.f;
        if (prod > 0) val = ew[e] * __frsqrt_rn((float)prod);
        const int pos = atomicAdd(&cursor[col], 1);
        pairbuf[offsets[col] + pos] = make_int2(row, __float_as_int(val));
        return;
    }
    if (bid >= 1024) {   // vbar: mean over heads
        const int idx = (bid - 1024) * 1024 + t * 4;
        const int n = idx >> 6, d0 = idx & 63;
        const ushort* vr = &v16[(size_t)n * HD + d0];
        float4 o;
        float* op = (float*)&o;
#pragma unroll
        for (int j = 0; j < 4; ++j)
            op[j] = 0.25f * (bf2f(vr[j]) + bf2f(vr[64 + j]) +
                             bf2f(vr[128 + j]) + bf2f(vr[192 + j]));
        *(float4*)&vbar[idx] = o;
        return;
    }

    const int h = bid & 3, b = (bid >> 2) & 63, z = bid >> 8;
    const int l = t & 63, w = t >> 6;
    const size_t base = (size_t)b * MM * HD + (size_t)h * DD;
    const int m0 = z * 128;

    {
        const int mat = t >> 7;
        const int u = t & 63;
        const int dhalf = (t >> 6) & 1;
        const int r0 = 2 * u;
        const int d0 = dhalf * 32;
        const ushort* src = mat ? v16 : k16;
        ushort* dst = mat ? vT : kT;
        const ushort* p0 = &src[base + (size_t)(m0 + r0) * HD + d0];
        const ushort* p1 = p0 + HD;
        u16x8 ra[4], rb[4];
#pragma unroll
        for (int i = 0; i < 4; ++i) ra[i] = *(const u16x8*)(p0 + 8 * i);
#pragma unroll
        for (int i = 0; i < 4; ++i) rb[i] = *(const u16x8*)(p1 + 8 * i);
#pragma unroll
        for (int i = 0; i < 4; ++i)
#pragma unroll
            for (int jj = 0; jj < 8; ++jj) {
                const int d = d0 + 8 * i + jj;
                uint pk = (uint)ra[i][jj] | ((uint)rb[i][jj] << 16);
                *(uint*)&dst[d * KVP + r0] = pk;
            }
    }
    __syncthreads();

    const int fr = l & 15, q4 = l >> 4, kg = q4 * 8;
    const int wr2 = (w & 1) * 32, wc2 = (w >> 1) * 32;
    s16x8 ones;
#pragma unroll
    for (int i = 0; i < 8; ++i) ones[i] = (short)0x3F80;

    f32x4 acc[2][2] = {};
    f32x4 aks[2] = {};
    f32x4 avs[2] = {};
#pragma unroll
    for (int s = 0; s < 4; ++s) {
        const int mo = s * 32 + kg;
        s16x8 af[2], bf[2];
        af[0] = *(const s16x8*)&kT[(wr2 + fr) * KVP + mo];
        af[1] = *(const s16x8*)&kT[(wr2 + 16 + fr) * KVP + mo];
        bf[0] = *(const s16x8*)&vT[(wc2 + fr) * KVP + mo];
        bf[1] = *(const s16x8*)&vT[(wc2 + 16 + fr) * KVP + mo];
#pragma unroll
        for (int il = 0; il < 2; ++il)
#pragma unroll
            for (int jl = 0; jl < 2; ++jl)
                acc[il][jl] = __builtin_amdgcn_mfma_f32_16x16x32_bf16(
                    af[il], bf[jl], acc[il][jl], 0, 0, 0);
#pragma unroll
        for (int il = 0; il < 2; ++il)
            aks[il] = __builtin_amdgcn_mfma_f32_16x16x32_bf16(
                af[il], ones, aks[il], 0, 0, 0);
#pragma unroll
        for (int jl = 0; jl < 2; ++jl)
            avs[jl] = __builtin_amdgcn_mfma_f32_16x16x32_bf16(
                ones, bf[jl], avs[jl], 0, 0, 0);
    }

    float* kvb = &kv_p[(((size_t)b * HH + h) * 4 + z) * 4096];
#pragma unroll
    for (int jl = 0; jl < 2; ++jl) {
        const int dv = wc2 + 16 * jl + fr;
#pragma unroll
        for (int il = 0; il < 2; ++il) {
            const int dk = wr2 + 16 * il + q4 * 4;
            *(f32x4*)&kvb[(size_t)dv * 64 + dk] = acc[il][jl];
        }
    }
    float* ksb = &ksum_p[(((size_t)b * HH + h) * 4 + z) * 64];
    float* vsb = &vsum_p[(((size_t)b * HH + h) * 4 + z) * 64];
    if (wc2 == 0 && fr == 0) {
#pragma unroll
        for (int il = 0; il < 2; ++il)
#pragma unroll
            for (int m = 0; m < 4; ++m)
                ksb[wr2 + 16 * il + q4 * 4 + m] = aks[il][m];
    }
    if (wr2 == 0 && l < 16) {
        vsb[wc2 + l]      = avs[0][0];
        vsb[wc2 + 16 + l] = avs[1][0];
    }
}

// ---------------------------------------------------------------------------
// K4: kv_red (blocks 0..1023) ∪ sumred (1024..1151).
// ---------------------------------------------------------------------------
__global__ __launch_bounds__(256) void red_kernel(
    const float* __restrict__ kv_p, const float* __restrict__ ksum_p,
    const float* __restrict__ vsum_p,
    ushort* __restrict__ kv16, float* __restrict__ ksum_f, float* __restrict__ vsum_f)
{
    const int bid = blockIdx.x;
    const int t = threadIdx.x;

    if (bid < 1024) {          // kv_red: 4 outputs/thread
        const int o4 = bid * 1024 + t * 4;
        const int bh = o4 >> 12, off = o4 & 4095;
        const float* p = &kv_p[(size_t)bh * 16384 + off];
        float4 s0 = *(const float4*)p;
        float4 s1 = *(const float4*)(p + 4096);
        float4 s2 = *(const float4*)(p + 8192);
        float4 s3 = *(const float4*)(p + 12288);
        const float r0 = s0.x + s1.x + s2.x + s3.x;
        const float r1 = s0.y + s1.y + s2.y + s3.y;
        const float r2 = s0.z + s1.z + s2.z + s3.z;
        const float r3 = s0.w + s1.w + s2.w + s3.w;
        uint2 pk = make_uint2(pkbf(r0, r1), pkbf(r2, r3));
        *(uint2*)&kv16[(size_t)bh * 4096 + off] = pk;
    } else {                   // ksum/vsum reduce
        const int o = (bid - 1024) * 256 + t;    // 0..32767
        const float* src = (o < 16384) ? ksum_p : vsum_p;
        float* dst = (o < 16384) ? ksum_f : vsum_f;
        const int oo = o & 16383;
        const int bh = oo >> 6, d = oo & 63;
        const float* p = &src[(size_t)bh * 256 + d];
        dst[oo] = p[0] + p[64] + p[128] + p[192];
    }
}

// ---------------------------------------------------------------------------
// K5: attn (512 virtual blocks) ∪ gcn gather (2048 virtual blocks), fused.
// Both atomically add into pre-zeroed out; interleaved bid%5 for overlap.
// ---------------------------------------------------------------------------
#define AKP 72
__global__ __launch_bounds__(256) void attn_gcn(
    const ushort* __restrict__ q16, const ushort* __restrict__ kv16,
    const float* __restrict__ ksum_f, const float* __restrict__ vsum_f,
    const float* __restrict__ sumsq,
    const int* __restrict__ n_nodes, float* __restrict__ out,
    const int* __restrict__ offsets, const int2* __restrict__ pairbuf,
    const float* __restrict__ vbar)
{
    const int bid = blockIdx.x;   // 2560 total
    const int t = threadIdx.x;
    const int l = t & 63;

    if (bid % 5 != 0) {   // ---- gcn: 2048 virtual blocks ----
        const int gid = bid - bid / 5 - 1;
        const int gt = gid * 256 + t;          // NN*16 threads
        const int n = gt >> 4;
        const int j = l & 15;                   // lane-in-group = d4 index
        const int d4 = j << 2;
        const int gl = l & 48;                  // group base lane
        const int s = offsets[n], e = offsets[n + 1];
        float ax = 0.f, ay = 0.f, az = 0.f, aw = 0.f;
        for (int base = s; base < e; base += 16) {
            const int cnt = min(16, e - base);
            int2 p = make_int2(0, 0);
            if (base + j < e) p = pairbuf[base + j];
            for (int jj = 0; jj < cnt; ++jj) {
                const int   row = __shfl(p.x, gl + jj, 64);
                const float val = __uint_as_float((uint)__shfl(p.y, gl + jj, 64));
                const float4 v = *(const float4*)&vbar[(size_t)row * DD + d4];
                ax += val * v.x; ay += val * v.y;
                az += val * v.z; aw += val * v.w;
            }
        }
        float* op = &out[(size_t)n * DD + d4];
        atomicAdd(op + 0, ax); atomicAdd(op + 1, ay);
        atomicAdd(op + 2, az); atomicAdd(op + 3, aw);
        return;
    }

    // ---- attn: 512 virtual blocks ----
    const int aid = bid / 5;
    const int b = aid >> 3;
    const int m0 = (aid & 7) * 64;
    const int w = t >> 6;
    const int fr = l & 15, q4 = l >> 4;
    const int wn = (w & 1) * 32, wd = (w >> 1) * 32;

    __shared__ ushort kvbf[64 * AKP];
    __shared__ float ksum_l[64], vsum_l[64], denom_l[64];

    const float nn = (float)n_nodes[b];
    const float inv = 1.0f / (sqrtf(sumsq[0]) * sqrtf(sumsq[1]));
    f32x4 acco[2][2] = {};

    for (int h = 0; h < HH; ++h) {
        __syncthreads();
        {   // stage bf16 KV [dv][dk]
            const int dv = t >> 2, dk0 = (t & 3) * 16;
            const ushort* kvg = &kv16[((size_t)(b * HH + h)) * 4096 + dv * 64 + dk0];
            *(uint4*)&kvbf[dv * AKP + dk0]     = *(const uint4*)kvg;
            *(uint4*)&kvbf[dv * AKP + dk0 + 8] = *(const uint4*)(kvg + 8);
        }
        if (t >= 64 && t < 128)
            ksum_l[t - 64] = ksum_f[((size_t)(b * HH + h)) * 64 + t - 64];
        else if (t >= 128 && t < 192)
            vsum_l[t - 128] = vsum_f[((size_t)(b * HH + h)) * 64 + t - 128];
        __syncthreads();

        {   // denominators: 4 lanes x 16 MACs per row, all 256 threads
            const int r = t >> 2, qq = t & 3;
            const ushort* qr = &q16[((size_t)(b * MM + m0 + r)) * HD + h * DD + qq * 16];
            float dsum = 0.f;
#pragma unroll
            for (int c = 0; c < 2; ++c) {
                u16x8 qv = *(const u16x8*)(qr + 8 * c);
#pragma unroll
                for (int j2 = 0; j2 < 8; ++j2)
                    dsum += bf2f(qv[j2]) * ksum_l[qq * 16 + 8 * c + j2];
            }
            dsum += __shfl_xor(dsum, 1, 64);
            dsum += __shfl_xor(dsum, 2, 64);
            if (qq == 0) denom_l[r] = nn + inv * dsum;
        }
        __syncthreads();

        f32x4 pacc[2][2] = {};
#pragma unroll
        for (int kx = 0; kx < 2; ++kx) {
            const int k0 = kx * 32;
            s16x8 af[2], bf[2];
#pragma unroll
            for (int il = 0; il < 2; ++il)
                af[il] = *(const s16x8*)&q16[
                    ((size_t)(b * MM + m0 + wn + 16 * il + fr)) * HD + h * DD + k0 + q4 * 8];
#pragma unroll
            for (int jl = 0; jl < 2; ++jl)
                bf[jl] = *(const s16x8*)&kvbf[(wd + 16 * jl + fr) * AKP + k0 + q4 * 8];
#pragma unroll
            for (int il = 0; il < 2; ++il)
#pragma unroll
                for (int jl = 0; jl < 2; ++jl)
                    pacc[il][jl] = __builtin_amdgcn_mfma_f32_16x16x32_bf16(
                        af[il], bf[jl], pacc[il][jl], 0, 0, 0);
        }
#pragma unroll
        for (int il = 0; il < 2; ++il)
#pragma unroll
            for (int m = 0; m < 4; ++m) {
                const float rden = 0.25f / denom_l[wn + 16 * il + q4 * 4 + m];
#pragma unroll
                for (int jl = 0; jl < 2; ++jl) {
                    const int d = wd + 16 * jl + fr;
                    acco[il][jl][m] += (inv * pacc[il][jl][m] + vsum_l[d]) * rden;
                }
            }
    }

#pragma unroll
    for (int il = 0; il < 2; ++il)
#pragma unroll
        for (int m = 0; m < 4; ++m) {
            const size_t node = (size_t)b * MM + m0 + wn + 16 * il + q4 * 4 + m;
#pragma unroll
            for (int jl = 0; jl < 2; ++jl)
                atomicAdd(&out[node * DD + wd + 16 * jl + fr], acco[il][jl][m]);
        }
}

// ---------------------------------------------------------------------------
extern "C" void kernel_launch(void* const* d_in, const int* in_sizes, int n_in,
                              void* d_out, int out_size, void* d_ws, size_t ws_size,
                              hipStream_t stream)
{
    (void)in_sizes; (void)n_in; (void)out_size; (void)ws_size;
    const float* Xq = (const float*)d_in[0];
    const float* Xs = (const float*)d_in[1];
    const float* ew = (const float*)d_in[2];
    const float* Wq = (const float*)d_in[3];
    const float* bq = (const float*)d_in[4];
    const float* Wk = (const float*)d_in[5];
    const float* bk = (const float*)d_in[6];
    const float* Wv = (const float*)d_in[7];
    const float* bv = (const float*)d_in[8];
    const int* n_nodes = (const int*)d_in[9];
    const int* ei = (const int*)d_in[10];
    float* out = (float*)d_out;
    float* ws  = (float*)d_ws;

    // workspace layout (float units); q/k/v bf16
    const size_t SZ_QKV   = (size_t)NN * HD / 2;       // 4194304 each
    const size_t OFF_Q    = 0;
    const size_t OFF_K    = SZ_QKV;
    const size_t OFF_V    = SZ_QKV * 2;
    const size_t OFF_SS   = SZ_QKV * 3;                // 16 floats (zeroed)
    const size_t OFF_DEG  = OFF_SS + 16;               // NN ints (zeroed)
    const size_t OFF_CUR  = OFF_DEG + NN;              // NN ints (zeroed)
    const size_t OFF_WT   = OFF_CUR + NN;              // 3*65536 ushorts
    const size_t OFF_OFFS = OFF_WT + 3 * 65536 / 2;    // NN+1 (+pad)
    const size_t OFF_UNI  = OFF_OFFS + NN + 16;
    // phase 1 (prep + qkv_scan): Xq16, Xs16 bf16 copies of inputs
    const size_t OFF_XQ16 = OFF_UNI;                   // XSZ/2 = 4194304
    const size_t OFF_XS16 = OFF_UNI + XSZ / 2;         // 4194304
    // phase 2 (kv_vbar onward) — Xq16/Xs16 dead, region reused:
    const size_t OFF_KV   = OFF_UNI;                                  // 4194304
    const size_t OFF_KSP  = OFF_KV + (size_t)BB * HH * 4 * 4096;      // 65536
    const size_t OFF_VSP  = OFF_KSP + (size_t)BB * HH * 4 * 64;       // 65536
    const size_t OFF_KV16 = OFF_VSP + (size_t)BB * HH * 4 * 64;       // 524288
    const size_t OFF_KSF  = OFF_KV16 + (size_t)BB * HH * 4096 / 2;    // 16384
    const size_t OFF_VSF  = OFF_KSF + (size_t)BB * HH * 64;           // 16384
    const size_t OFF_PAIR = OFF_VSF + (size_t)BB * HH * 64;           // 1048576
    const size_t OFF_VBAR = OFF_PAIR + 2 * (size_t)EE;                // 2097152
    // phase-2 extent fits inside phase-1 union; total ws ≈ 85 MB

    ushort* q16   = (ushort*)(ws + OFF_Q);
    ushort* k16   = (ushort*)(ws + OFF_K);
    ushort* v16   = (ushort*)(ws + OFF_V);
    float* sumsq  = ws + OFF_SS;
    int*   deg    = (int*)(ws + OFF_DEG);
    int*   cursor = (int*)(ws + OFF_CUR);
    ushort* WT    = (ushort*)(ws + OFF_WT);
    int*   offs   = (int*)(ws + OFF_OFFS);
    ushort* xq16  = (ushort*)(ws + OFF_XQ16);
    ushort* xs16  = (ushort*)(ws + OFF_XS16);
    float* kv_p   = ws + OFF_KV;
    float* ksum_p = ws + OFF_KSP;
    float* vsum_p = ws + OFF_VSP;
    ushort* kv16  = (ushort*)(ws + OFF_KV16);
    float* ksum_f = ws + OFF_KSF;
    float* vsum_f = ws + OFF_VSF;
    int2*  pairb  = (int2*)(ws + OFF_PAIR);
    float* vbar   = ws + OFF_VBAR;

    // zero sumsq + deg + cursor (contiguous) and out (atomic accumulation)
    hipMemsetAsync(sumsq, 0, (16 + 2 * NN) * sizeof(float), stream);
    hipMemsetAsync(out, 0, (size_t)NN * DD * sizeof(float), stream);
    prep_kernel<<<11008, 256, 0, stream>>>(Wq, Wk, Wv, WT, ei, deg, Xq, Xs, xq16, xs16);
    qkv_scan<<<1537, 256, 0, stream>>>(
        xq16, xs16, WT, bq, bk, bv, q16, k16, v16, sumsq, deg, offs);
    kv_vbar_bucket<<<5120, 256, 0, stream>>>(
        k16, v16, kv_p, ksum_p, vsum_p, vbar, ei, ew, deg, offs, cursor, pairb);
    red_kernel<<<1152, 256, 0, stream>>>(
        kv_p, ksum_p, vsum_p, kv16, ksum_f, vsum_f);
    attn_gcn<<<2560, 256, 0, stream>>>(
        q16, kv16, ksum_f, vsum_f, sumsq, n_nodes, out, offs, pairb, vbar);
}

// Round 4
// 257.893 us; speedup vs baseline: 1.1488x; 1.1017x over previous
//
#include <hip/hip_runtime.h>
#include <hip/hip_bf16.h>

#define NN 32768   // nodes
#define BB 64      // graphs
#define MM 512     // nodes per graph
#define HH 4       // heads
#define DD 64      // head dim
#define INF 256    // input features
#define HD 256     // H*D
#define EE 524288  // edges
#define XSZ 8388608  // NN*INF elements per X matrix

typedef unsigned short ushort;
typedef unsigned int uint;
typedef short s16x8 __attribute__((ext_vector_type(8)));
typedef ushort u16x8 __attribute__((ext_vector_type(8)));
typedef float f32x4 __attribute__((ext_vector_type(4)));

__device__ __forceinline__ ushort f2bf(float f) {
    uint u = __float_as_uint(f);
    return (ushort)((u + 0x7fffu + ((u >> 16) & 1u)) >> 16);
}
__device__ __forceinline__ float bf2f(ushort u) {
    return __uint_as_float((uint)u << 16);
}
__device__ __forceinline__ uint pkbf(float x, float y) {
    __hip_bfloat162 h = __float22bfloat162_rn(make_float2(x, y));
    return *(uint*)&h;
}

#define GLD16(gp, lp) __builtin_amdgcn_global_load_lds( \
    (const __attribute__((address_space(1))) void*)(gp), \
    (__attribute__((address_space(3))) void*)(lp), 16, 0, 0)

// ---------------------------------------------------------------------------
// K1: convert_w (blocks 0..767) ∪ deg histogram (blocks 768..2815) ∪
//     X f32->bf16 convert (blocks 2816..11007).
// ---------------------------------------------------------------------------
__global__ __launch_bounds__(256) void prep_kernel(
    const float* __restrict__ Wq, const float* __restrict__ Wk,
    const float* __restrict__ Wv, ushort* __restrict__ WT,
    const int* __restrict__ ei, int* __restrict__ deg,
    const float* __restrict__ Xq, const float* __restrict__ Xs,
    ushort* __restrict__ xq16, ushort* __restrict__ xs16)
{
    const int bid = blockIdx.x;
    if (bid < 768) {
        const int id = bid * 256 + threadIdx.x;      // 3*65536
        const int mat = id >> 16, rem = id & 65535;
        const int n = rem >> 8, kk = rem & 255;
        const float* W = (mat == 0) ? Wq : (mat == 1) ? Wk : Wv;
        WT[id] = f2bf(W[kk * 256 + n]);              // WT[mat][n][kk]
    } else if (bid < 2816) {
        const int e = (bid - 768) * 256 + threadIdx.x;   // EE total
        atomicAdd(&deg[ei[EE + e]], 1);
    } else {
        const size_t id = (size_t)(bid - 2816) * 256 + threadIdx.x;
        const size_t o8 = id * 8;                    // 8 floats / thread
        const float* src; ushort* dst; size_t o;
        if (o8 < XSZ) { src = Xq; dst = xq16; o = o8; }
        else          { src = Xs; dst = xs16; o = o8 - XSZ; }
        const float4 f0 = *(const float4*)(src + o);
        const float4 f1 = *(const float4*)(src + o + 4);
        u16x8 r;
        r[0] = f2bf(f0.x); r[1] = f2bf(f0.y); r[2] = f2bf(f0.z); r[3] = f2bf(f0.w);
        r[4] = f2bf(f1.x); r[5] = f2bf(f1.y); r[6] = f2bf(f1.z); r[7] = f2bf(f1.w);
        *(u16x8*)(dst + o) = r;
    }
}

// ---------------------------------------------------------------------------
// K2: qkv GEMM (blocks 0..1535) ∪ scan (block 1536).
// T4-pipelined: 3 LDS buffers, counted s_waitcnt vmcnt(4) before raw
// s_barrier, stage issued AFTER the barrier (race-free: readers' ds_reads
// are consumed before they reach the barrier preceding the overwrite).
// Loads get 2 compute phases of flight; vmcnt never drains to 0 mid-loop.
// ---------------------------------------------------------------------------
__global__ __launch_bounds__(256) void qkv_scan(
    const ushort* __restrict__ Xq16, const ushort* __restrict__ Xs16,
    const ushort* __restrict__ WT,
    const float* __restrict__ bq, const float* __restrict__ bk,
    const float* __restrict__ bv,
    ushort* __restrict__ qo, ushort* __restrict__ ko, ushort* __restrict__ vo,
    float* __restrict__ sumsq,
    const int* __restrict__ deg, int* __restrict__ offsets)
{
    __shared__ ushort As[3][128 * 32];
    __shared__ ushort Bs[3][128 * 32];
    __shared__ float wred[4];
    __shared__ int part[256];

    const int id = blockIdx.x;
    const int t = threadIdx.x;

    if (id == 1536) {   // exclusive scan of deg -> offsets, 128 elems/thread
        const int base = t * 128;
        int s = 0;
        for (int i = 0; i < 128; ++i) s += deg[base + i];
        part[t] = s;
        __syncthreads();
        for (int off = 1; off < 256; off <<= 1) {
            int a = part[t];
            int b2 = (t >= off) ? part[t - off] : 0;
            __syncthreads();
            part[t] = a + b2;
            __syncthreads();
        }
        int run = (t == 0) ? 0 : part[t - 1];
        for (int i = 0; i < 128; ++i) { offsets[base + i] = run; run += deg[base + i]; }
        if (t == 255) offsets[NN] = run;
        return;
    }

    const int vv = (id & 7) * 192 + (id >> 3);   // XCD-contiguous row-groups
    const int rt = vv / 6, ct = vv % 6;
    const int wsel = ct >> 1;                    // 0:q 1:k 2:v
    const ushort* A16 = (wsel == 0) ? Xq16 : Xs16;
    const ushort* W   = WT + (size_t)wsel * 65536;
    const float* bias = (wsel == 0) ? bq : (wsel == 1) ? bk : bv;
    ushort* C         = (wsel == 0) ? qo : (wsel == 1) ? ko : vo;
    const int row0 = rt * 128;
    const int col0 = (ct & 1) * 128;

    const int l = t & 63, w = t >> 6;
    const int fr = l & 15, q4 = l >> 4;
    const int wr = (w & 1) * 64, wc = (w >> 1) * 64;

    // staging: per wave, 64 lanes x 16B contiguous LDS
    const int srow = (w << 4) + (l >> 2);        // 0..63 within 64-row half
    const int scol = (l & 3) << 3;               // 0,8,16,24
    const ushort* ga = &A16[(size_t)(row0 + srow) * INF + scol];
    const ushort* gb = &W  [(size_t)(col0 + srow) * INF + scol];
    const int lbase = (w << 9);                  // wave-uniform ushort offset

    f32x4 acc[4][4] = {};

#define QKV_STAGE(bufi, k0) \
    GLD16(ga + (k0),            &As[bufi][lbase]); \
    GLD16(ga + (k0) + 64 * INF, &As[bufi][2048 + lbase]); \
    GLD16(gb + (k0),            &Bs[bufi][lbase]); \
    GLD16(gb + (k0) + 64 * INF, &Bs[bufi][2048 + lbase]);

#define QKV_COMPUTE(bufi) { \
    const int kg = q4 * 8; \
    s16x8 af[4], bfr[4]; \
    _Pragma("unroll") \
    for (int i = 0; i < 4; ++i) \
        af[i] = *(const s16x8*)&As[bufi][(wr + i * 16 + fr) * 32 + kg]; \
    _Pragma("unroll") \
    for (int j = 0; j < 4; ++j) \
        bfr[j] = *(const s16x8*)&Bs[bufi][(wc + j * 16 + fr) * 32 + kg]; \
    _Pragma("unroll") \
    for (int i = 0; i < 4; ++i) \
    _Pragma("unroll") \
        for (int j = 0; j < 4; ++j) \
            acc[i][j] = __builtin_amdgcn_mfma_f32_16x16x32_bf16( \
                af[i], bfr[j], acc[i][j], 0, 0, 0); }

#define WAIT4 asm volatile("s_waitcnt vmcnt(4)" ::: "memory")
#define WAIT0 asm volatile("s_waitcnt vmcnt(0)" ::: "memory")
#define BAR   __builtin_amdgcn_s_barrier()

    // prologue: buffers 0 and 1 in flight
    QKV_STAGE(0, 0)
    QKV_STAGE(1, 32)

    WAIT4; BAR; QKV_STAGE(2,  64) QKV_COMPUTE(0)   // it0
    WAIT4; BAR; QKV_STAGE(0,  96) QKV_COMPUTE(1)   // it1
    WAIT4; BAR; QKV_STAGE(1, 128) QKV_COMPUTE(2)   // it2
    WAIT4; BAR; QKV_STAGE(2, 160) QKV_COMPUTE(0)   // it3
    WAIT4; BAR; QKV_STAGE(0, 192) QKV_COMPUTE(1)   // it4
    WAIT4; BAR; QKV_STAGE(1, 224) QKV_COMPUTE(2)   // it5
    WAIT4; BAR;                   QKV_COMPUTE(0)   // it6
    WAIT0; BAR;                   QKV_COMPUTE(1)   // it7

    float loc = 0.f;
#pragma unroll
    for (int j = 0; j < 4; ++j) {
        const int colg = col0 + wc + j * 16 + fr;
        const float bj = bias[colg];
#pragma unroll
        for (int i = 0; i < 4; ++i) {
            const int rowg = row0 + wr + i * 16 + q4 * 4;
#pragma unroll
            for (int m = 0; m < 4; ++m) {
                float cv = acc[i][j][m] + bj;
                loc += cv * cv;
                C[(size_t)(rowg + m) * HD + colg] = f2bf(cv);
            }
        }
    }
    if (wsel < 2) {
#pragma unroll
        for (int off = 32; off > 0; off >>= 1) loc += __shfl_down(loc, off, 64);
        if (l == 0) wred[w] = loc;
        __syncthreads();
        if (t == 0) atomicAdd(&sumsq[wsel], wred[0] + wred[1] + wred[2] + wred[3]);
    }
}

// ---------------------------------------------------------------------------
// K3: kv_mfma (blocks 0..1023) ∪ vbar (blocks 1024..3071, 4 elems/thread).
// kv parts stored transposed [dv][dk] for attn's B-operand layout.
// ---------------------------------------------------------------------------
#define KVP 136
__global__ __launch_bounds__(256) void kv_vbar(
    const ushort* __restrict__ k16, const ushort* __restrict__ v16,
    float* __restrict__ kv_p, float* __restrict__ ksum_p, float* __restrict__ vsum_p,
    float* __restrict__ vbar)
{
    __shared__ ushort kT[64 * KVP];
    __shared__ ushort vT[64 * KVP];
    const int bid = blockIdx.x;
    const int t = threadIdx.x;

    if (bid >= 1024) {   // vbar: mean over heads
        const int idx = (bid - 1024) * 1024 + t * 4;
        const int n = idx >> 6, d0 = idx & 63;
        const ushort* vr = &v16[(size_t)n * HD + d0];
        float4 o;
        float* op = (float*)&o;
#pragma unroll
        for (int j = 0; j < 4; ++j)
            op[j] = 0.25f * (bf2f(vr[j]) + bf2f(vr[64 + j]) +
                             bf2f(vr[128 + j]) + bf2f(vr[192 + j]));
        *(float4*)&vbar[idx] = o;
        return;
    }

    const int h = bid & 3, b = (bid >> 2) & 63, z = bid >> 8;
    const int l = t & 63, w = t >> 6;
    const size_t base = (size_t)b * MM * HD + (size_t)h * DD;
    const int m0 = z * 128;

    {
        const int mat = t >> 7;
        const int u = t & 63;
        const int dhalf = (t >> 6) & 1;
        const int r0 = 2 * u;
        const int d0 = dhalf * 32;
        const ushort* src = mat ? v16 : k16;
        ushort* dst = mat ? vT : kT;
        const ushort* p0 = &src[base + (size_t)(m0 + r0) * HD + d0];
        const ushort* p1 = p0 + HD;
        u16x8 ra[4], rb[4];
#pragma unroll
        for (int i = 0; i < 4; ++i) ra[i] = *(const u16x8*)(p0 + 8 * i);
#pragma unroll
        for (int i = 0; i < 4; ++i) rb[i] = *(const u16x8*)(p1 + 8 * i);
#pragma unroll
        for (int i = 0; i < 4; ++i)
#pragma unroll
            for (int jj = 0; jj < 8; ++jj) {
                const int d = d0 + 8 * i + jj;
                uint pk = (uint)ra[i][jj] | ((uint)rb[i][jj] << 16);
                *(uint*)&dst[d * KVP + r0] = pk;
            }
    }
    __syncthreads();

    const int fr = l & 15, q4 = l >> 4, kg = q4 * 8;
    const int wr2 = (w & 1) * 32, wc2 = (w >> 1) * 32;
    s16x8 ones;
#pragma unroll
    for (int i = 0; i < 8; ++i) ones[i] = (short)0x3F80;

    f32x4 acc[2][2] = {};
    f32x4 aks[2] = {};
    f32x4 avs[2] = {};
#pragma unroll
    for (int s = 0; s < 4; ++s) {
        const int mo = s * 32 + kg;
        s16x8 af[2], bf[2];
        af[0] = *(const s16x8*)&kT[(wr2 + fr) * KVP + mo];
        af[1] = *(const s16x8*)&kT[(wr2 + 16 + fr) * KVP + mo];
        bf[0] = *(const s16x8*)&vT[(wc2 + fr) * KVP + mo];
        bf[1] = *(const s16x8*)&vT[(wc2 + 16 + fr) * KVP + mo];
#pragma unroll
        for (int il = 0; il < 2; ++il)
#pragma unroll
            for (int jl = 0; jl < 2; ++jl)
                acc[il][jl] = __builtin_amdgcn_mfma_f32_16x16x32_bf16(
                    af[il], bf[jl], acc[il][jl], 0, 0, 0);
#pragma unroll
        for (int il = 0; il < 2; ++il)
            aks[il] = __builtin_amdgcn_mfma_f32_16x16x32_bf16(
                af[il], ones, aks[il], 0, 0, 0);
#pragma unroll
        for (int jl = 0; jl < 2; ++jl)
            avs[jl] = __builtin_amdgcn_mfma_f32_16x16x32_bf16(
                ones, bf[jl], avs[jl], 0, 0, 0);
    }

    float* kvb = &kv_p[(((size_t)b * HH + h) * 4 + z) * 4096];
#pragma unroll
    for (int jl = 0; jl < 2; ++jl) {
        const int dv = wc2 + 16 * jl + fr;
#pragma unroll
        for (int il = 0; il < 2; ++il) {
            const int dk = wr2 + 16 * il + q4 * 4;
            *(f32x4*)&kvb[(size_t)dv * 64 + dk] = acc[il][jl];
        }
    }
    float* ksb = &ksum_p[(((size_t)b * HH + h) * 4 + z) * 64];
    float* vsb = &vsum_p[(((size_t)b * HH + h) * 4 + z) * 64];
    if (wc2 == 0 && fr == 0) {
#pragma unroll
        for (int il = 0; il < 2; ++il)
#pragma unroll
            for (int m = 0; m < 4; ++m)
                ksb[wr2 + 16 * il + q4 * 4 + m] = aks[il][m];
    }
    if (wr2 == 0 && l < 16) {
        vsb[wc2 + l]      = avs[0][0];
        vsb[wc2 + 16 + l] = avs[1][0];
    }
}

// ---------------------------------------------------------------------------
// K4: kv_red (blocks 0..1023) ∪ sumred (1024..1151) ∪ bucket (1152..3199).
// ---------------------------------------------------------------------------
__global__ __launch_bounds__(256) void red_bucket(
    const float* __restrict__ kv_p, const float* __restrict__ ksum_p,
    const float* __restrict__ vsum_p,
    ushort* __restrict__ kv16, float* __restrict__ ksum_f, float* __restrict__ vsum_f,
    const int* __restrict__ ei, const float* __restrict__ ew,
    const int* __restrict__ deg, const int* __restrict__ offsets,
    int* __restrict__ cursor, int2* __restrict__ pairbuf)
{
    const int bid = blockIdx.x;
    const int t = threadIdx.x;

    if (bid < 1024) {          // kv_red: 4 outputs/thread
        const int o4 = bid * 1024 + t * 4;
        const int bh = o4 >> 12, off = o4 & 4095;
        const float* p = &kv_p[(size_t)bh * 16384 + off];
        float4 s0 = *(const float4*)p;
        float4 s1 = *(const float4*)(p + 4096);
        float4 s2 = *(const float4*)(p + 8192);
        float4 s3 = *(const float4*)(p + 12288);
        const float r0 = s0.x + s1.x + s2.x + s3.x;
        const float r1 = s0.y + s1.y + s2.y + s3.y;
        const float r2 = s0.z + s1.z + s2.z + s3.z;
        const float r3 = s0.w + s1.w + s2.w + s3.w;
        uint2 pk = make_uint2(pkbf(r0, r1), pkbf(r2, r3));
        *(uint2*)&kv16[(size_t)bh * 4096 + off] = pk;
    } else if (bid < 1152) {   // ksum/vsum reduce
        const int o = (bid - 1024) * 256 + t;    // 0..32767
        const float* src = (o < 16384) ? ksum_p : vsum_p;
        float* dst = (o < 16384) ? ksum_f : vsum_f;
        const int oo = o & 16383;
        const int bh = oo >> 6, d = oo & 63;
        const float* p = &src[(size_t)bh * 256 + d];
        dst[oo] = p[0] + p[64] + p[128] + p[192];
    } else {                   // bucket
        const int e = (bid - 1152) * 256 + t;
        const int row = ei[e], col = ei[EE + e];
        const long long prod = (long long)deg[row] * (long long)deg[col];
        float val = 0.f;
        if (prod > 0) val = ew[e] * __frsqrt_rn((float)prod);
        const int pos = atomicAdd(&cursor[col], 1);
        pairbuf[offsets[col] + pos] = make_int2(row, __float_as_int(val));
    }
}

// ---------------------------------------------------------------------------
// K5: attn via MFMA. P = q[64x64] x KV^T; KV staged bf16 from kv16.
// Denominator phase parallelized over all 256 threads (4 lanes/row).
// ---------------------------------------------------------------------------
#define AKP 72
__global__ __launch_bounds__(256) void attn_mfma(
    const ushort* __restrict__ q16, const ushort* __restrict__ kv16,
    const float* __restrict__ ksum_f, const float* __restrict__ vsum_f,
    const float* __restrict__ sumsq,
    const int* __restrict__ n_nodes, float* __restrict__ out)
{
    const int b = blockIdx.y;
    const int m0 = blockIdx.x * 64;
    const int t = threadIdx.x;
    const int l = t & 63, w = t >> 6;
    const int fr = l & 15, q4 = l >> 4;
    const int wn = (w & 1) * 32, wd = (w >> 1) * 32;

    __shared__ ushort kvbf[64 * AKP];
    __shared__ float ksum_l[64], vsum_l[64], denom_l[64];

    const float nn = (float)n_nodes[b];
    const float inv = 1.0f / (sqrtf(sumsq[0]) * sqrtf(sumsq[1]));
    f32x4 acco[2][2] = {};

    for (int h = 0; h < HH; ++h) {
        __syncthreads();
        {   // stage bf16 KV [dv][dk]
            const int dv = t >> 2, dk0 = (t & 3) * 16;
            const ushort* kvg = &kv16[((size_t)(b * HH + h)) * 4096 + dv * 64 + dk0];
            *(uint4*)&kvbf[dv * AKP + dk0]     = *(const uint4*)kvg;
            *(uint4*)&kvbf[dv * AKP + dk0 + 8] = *(const uint4*)(kvg + 8);
        }
        if (t >= 64 && t < 128)
            ksum_l[t - 64] = ksum_f[((size_t)(b * HH + h)) * 64 + t - 64];
        else if (t >= 128 && t < 192)
            vsum_l[t - 128] = vsum_f[((size_t)(b * HH + h)) * 64 + t - 128];
        __syncthreads();

        {   // denominators: 4 lanes x 16 MACs per row, all 256 threads
            const int r = t >> 2, qq = t & 3;
            const ushort* qr = &q16[((size_t)(b * MM + m0 + r)) * HD + h * DD + qq * 16];
            float dsum = 0.f;
#pragma unroll
            for (int c = 0; c < 2; ++c) {
                u16x8 qv = *(const u16x8*)(qr + 8 * c);
#pragma unroll
                for (int j2 = 0; j2 < 8; ++j2)
                    dsum += bf2f(qv[j2]) * ksum_l[qq * 16 + 8 * c + j2];
            }
            dsum += __shfl_xor(dsum, 1, 64);
            dsum += __shfl_xor(dsum, 2, 64);
            if (qq == 0) denom_l[r] = nn + inv * dsum;
        }
        __syncthreads();

        f32x4 pacc[2][2] = {};
#pragma unroll
        for (int kx = 0; kx < 2; ++kx) {
            const int k0 = kx * 32;
            s16x8 af[2], bf[2];
#pragma unroll
            for (int il = 0; il < 2; ++il)
                af[il] = *(const s16x8*)&q16[
                    ((size_t)(b * MM + m0 + wn + 16 * il + fr)) * HD + h * DD + k0 + q4 * 8];
#pragma unroll
            for (int jl = 0; jl < 2; ++jl)
                bf[jl] = *(const s16x8*)&kvbf[(wd + 16 * jl + fr) * AKP + k0 + q4 * 8];
#pragma unroll
            for (int il = 0; il < 2; ++il)
#pragma unroll
                for (int jl = 0; jl < 2; ++jl)
                    pacc[il][jl] = __builtin_amdgcn_mfma_f32_16x16x32_bf16(
                        af[il], bf[jl], pacc[il][jl], 0, 0, 0);
        }
#pragma unroll
        for (int il = 0; il < 2; ++il)
#pragma unroll
            for (int m = 0; m < 4; ++m) {
                const float rden = 0.25f / denom_l[wn + 16 * il + q4 * 4 + m];
#pragma unroll
                for (int jl = 0; jl < 2; ++jl) {
                    const int d = wd + 16 * jl + fr;
                    acco[il][jl][m] += (inv * pacc[il][jl][m] + vsum_l[d]) * rden;
                }
            }
    }

#pragma unroll
    for (int il = 0; il < 2; ++il)
#pragma unroll
        for (int m = 0; m < 4; ++m) {
            const size_t node = (size_t)b * MM + m0 + wn + 16 * il + q4 * 4 + m;
#pragma unroll
            for (int jl = 0; jl < 2; ++jl)
                out[node * DD + wd + 16 * jl + fr] = acco[il][jl][m];
        }
}

// ---------------------------------------------------------------------------
// K6: GCN gather (packed pairbuf), float4 per thread: 16 threads/node.
// ---------------------------------------------------------------------------
__global__ __launch_bounds__(256) void gcn_gather(
    const int* __restrict__ offsets, const int2* __restrict__ pairbuf,
    const float* __restrict__ vbar, float* __restrict__ out)
{
    const int t = blockIdx.x * 256 + threadIdx.x;   // NN*16 threads
    const int n = t >> 4, d4 = (t & 15) << 2;
    const int s = offsets[n], e = offsets[n + 1];
    float ax = 0.f, ay = 0.f, az = 0.f, aw = 0.f;
    int i = s;
    for (; i + 2 <= e; i += 2) {
        const int2 p0 = pairbuf[i], p1 = pairbuf[i + 1];
        const float w0 = __int_as_float(p0.y), w1 = __int_as_float(p1.y);
        const float4 v0 = *(const float4*)&vbar[(size_t)p0.x * DD + d4];
        const float4 v1 = *(const float4*)&vbar[(size_t)p1.x * DD + d4];
        ax += w0 * v0.x + w1 * v1.x;
        ay += w0 * v0.y + w1 * v1.y;
        az += w0 * v0.z + w1 * v1.z;
        aw += w0 * v0.w + w1 * v1.w;
    }
    if (i < e) {
        const int2 p = pairbuf[i];
        const float wv = __int_as_float(p.y);
        const float4 v = *(const float4*)&vbar[(size_t)p.x * DD + d4];
        ax += wv * v.x; ay += wv * v.y; az += wv * v.z; aw += wv * v.w;
    }
    float4 o = *(float4*)&out[(size_t)n * DD + d4];
    o.x += ax; o.y += ay; o.z += az; o.w += aw;
    *(float4*)&out[(size_t)n * DD + d4] = o;
}

// ---------------------------------------------------------------------------
extern "C" void kernel_launch(void* const* d_in, const int* in_sizes, int n_in,
                              void* d_out, int out_size, void* d_ws, size_t ws_size,
                              hipStream_t stream)
{
    (void)in_sizes; (void)n_in; (void)out_size; (void)ws_size;
    const float* Xq = (const float*)d_in[0];
    const float* Xs = (const float*)d_in[1];
    const float* ew = (const float*)d_in[2];
    const float* Wq = (const float*)d_in[3];
    const float* bq = (const float*)d_in[4];
    const float* Wk = (const float*)d_in[5];
    const float* bk = (const float*)d_in[6];
    const float* Wv = (const float*)d_in[7];
    const float* bv = (const float*)d_in[8];
    const int* n_nodes = (const int*)d_in[9];
    const int* ei = (const int*)d_in[10];
    float* out = (float*)d_out;
    float* ws  = (float*)d_ws;

    // workspace layout (float units); q/k/v bf16
    const size_t SZ_QKV   = (size_t)NN * HD / 2;       // 4194304 each
    const size_t OFF_Q    = 0;
    const size_t OFF_K    = SZ_QKV;
    const size_t OFF_V    = SZ_QKV * 2;
    const size_t OFF_SS   = SZ_QKV * 3;                // 16 floats (zeroed)
    const size_t OFF_DEG  = OFF_SS + 16;               // NN ints (zeroed)
    const size_t OFF_CUR  = OFF_DEG + NN;              // NN ints (zeroed)
    const size_t OFF_WT   = OFF_CUR + NN;              // 3*65536 ushorts
    const size_t OFF_OFFS = OFF_WT + 3 * 65536 / 2;    // NN+1 (+pad)
    const size_t OFF_UNI  = OFF_OFFS + NN + 16;
    // phase 1 (prep + qkv_scan): Xq16, Xs16 bf16 copies of inputs
    const size_t OFF_XQ16 = OFF_UNI;                   // XSZ/2 = 4194304
    const size_t OFF_XS16 = OFF_UNI + XSZ / 2;         // 4194304
    // phase 2 (kv_vbar onward) — Xq16/Xs16 dead, region reused:
    const size_t OFF_KV   = OFF_UNI;                                  // 4194304
    const size_t OFF_KSP  = OFF_KV + (size_t)BB * HH * 4 * 4096;      // 65536
    const size_t OFF_VSP  = OFF_KSP + (size_t)BB * HH * 4 * 64;       // 65536
    const size_t OFF_KV16 = OFF_VSP + (size_t)BB * HH * 4 * 64;       // 524288
    const size_t OFF_KSF  = OFF_KV16 + (size_t)BB * HH * 4096 / 2;    // 16384
    const size_t OFF_VSF  = OFF_KSF + (size_t)BB * HH * 64;           // 16384
    const size_t OFF_PAIR = OFF_VSF + (size_t)BB * HH * 64;           // 1048576
    const size_t OFF_VBAR = OFF_PAIR + 2 * (size_t)EE;                // 2097152
    // phase-2 extent fits inside phase-1 union; total ws ≈ 85 MB

    ushort* q16   = (ushort*)(ws + OFF_Q);
    ushort* k16   = (ushort*)(ws + OFF_K);
    ushort* v16   = (ushort*)(ws + OFF_V);
    float* sumsq  = ws + OFF_SS;
    int*   deg    = (int*)(ws + OFF_DEG);
    int*   cursor = (int*)(ws + OFF_CUR);
    ushort* WT    = (ushort*)(ws + OFF_WT);
    int*   offs   = (int*)(ws + OFF_OFFS);
    ushort* xq16  = (ushort*)(ws + OFF_XQ16);
    ushort* xs16  = (ushort*)(ws + OFF_XS16);
    float* kv_p   = ws + OFF_KV;
    float* ksum_p = ws + OFF_KSP;
    float* vsum_p = ws + OFF_VSP;
    ushort* kv16  = (ushort*)(ws + OFF_KV16);
    float* ksum_f = ws + OFF_KSF;
    float* vsum_f = ws + OFF_VSF;
    int2*  pairb  = (int2*)(ws + OFF_PAIR);
    float* vbar   = ws + OFF_VBAR;

    // zero sumsq + deg + cursor (contiguous)
    hipMemsetAsync(sumsq, 0, (16 + 2 * NN) * sizeof(float), stream);
    prep_kernel<<<11008, 256, 0, stream>>>(Wq, Wk, Wv, WT, ei, deg, Xq, Xs, xq16, xs16);
    qkv_scan<<<1537, 256, 0, stream>>>(
        xq16, xs16, WT, bq, bk, bv, q16, k16, v16, sumsq, deg, offs);
    kv_vbar<<<3072, 256, 0, stream>>>(k16, v16, kv_p, ksum_p, vsum_p, vbar);
    red_bucket<<<3200, 256, 0, stream>>>(
        kv_p, ksum_p, vsum_p, kv16, ksum_f, vsum_f,
        ei, ew, deg, offs, cursor, pairb);
    attn_mfma<<<dim3(MM / 64, BB), 256, 0, stream>>>(
        q16, kv16, ksum_f, vsum_f, sumsq, n_nodes, out);
    gcn_gather<<<(NN * 16) / 256, 256, 0, stream>>>(offs, pairb, vbar, out);
}

// Round 5
// 255.530 us; speedup vs baseline: 1.1594x; 1.0092x over previous
//
#include <hip/hip_runtime.h>
#include <hip/hip_bf16.h>

#define NN 32768   // nodes
#define BB 64      // graphs
#define MM 512     // nodes per graph
#define HH 4       // heads
#define DD 64      // head dim
#define INF 256    // input features
#define HD 256     // H*D
#define EE 524288  // edges
#define XSZ 8388608  // NN*INF elements per X matrix

typedef unsigned short ushort;
typedef unsigned int uint;
typedef short s16x8 __attribute__((ext_vector_type(8)));
typedef ushort u16x8 __attribute__((ext_vector_type(8)));
typedef float f32x4 __attribute__((ext_vector_type(4)));

__device__ __forceinline__ ushort f2bf(float f) {
    uint u = __float_as_uint(f);
    return (ushort)((u + 0x7fffu + ((u >> 16) & 1u)) >> 16);
}
__device__ __forceinline__ float bf2f(ushort u) {
    return __uint_as_float((uint)u << 16);
}
__device__ __forceinline__ uint pkbf(float x, float y) {
    __hip_bfloat162 h = __float22bfloat162_rn(make_float2(x, y));
    return *(uint*)&h;
}

#define GLD16(gp, lp) __builtin_amdgcn_global_load_lds( \
    (const __attribute__((address_space(1))) void*)(gp), \
    (__attribute__((address_space(3))) void*)(lp), 16, 0, 0)

// ---------------------------------------------------------------------------
// K1: convert_w (blocks 0..767) ∪ deg histogram (blocks 768..2815) ∪
//     X f32->bf16 convert (blocks 2816..11007).
// ---------------------------------------------------------------------------
__global__ __launch_bounds__(256) void prep_kernel(
    const float* __restrict__ Wq, const float* __restrict__ Wk,
    const float* __restrict__ Wv, ushort* __restrict__ WT,
    const int* __restrict__ ei, int* __restrict__ deg,
    const float* __restrict__ Xq, const float* __restrict__ Xs,
    ushort* __restrict__ xq16, ushort* __restrict__ xs16)
{
    const int bid = blockIdx.x;
    if (bid < 768) {
        const int id = bid * 256 + threadIdx.x;      // 3*65536
        const int mat = id >> 16, rem = id & 65535;
        const int n = rem >> 8, kk = rem & 255;
        const float* W = (mat == 0) ? Wq : (mat == 1) ? Wk : Wv;
        WT[id] = f2bf(W[kk * 256 + n]);              // WT[mat][n][kk]
    } else if (bid < 2816) {
        const int e = (bid - 768) * 256 + threadIdx.x;   // EE total
        atomicAdd(&deg[ei[EE + e]], 1);
    } else {
        const size_t id = (size_t)(bid - 2816) * 256 + threadIdx.x;
        const size_t o8 = id * 8;                    // 8 floats / thread
        const float* src; ushort* dst; size_t o;
        if (o8 < XSZ) { src = Xq; dst = xq16; o = o8; }
        else          { src = Xs; dst = xs16; o = o8 - XSZ; }
        const float4 f0 = *(const float4*)(src + o);
        const float4 f1 = *(const float4*)(src + o + 4);
        u16x8 r;
        r[0] = f2bf(f0.x); r[1] = f2bf(f0.y); r[2] = f2bf(f0.z); r[3] = f2bf(f0.w);
        r[4] = f2bf(f1.x); r[5] = f2bf(f1.y); r[6] = f2bf(f1.z); r[7] = f2bf(f1.w);
        *(u16x8*)(dst + o) = r;
    }
}

// ---------------------------------------------------------------------------
// K2: qkv GEMM (blocks 0..1535) ∪ scan (block 1536).
// T4-pipelined: 3 LDS buffers, counted s_waitcnt vmcnt(4) before raw
// s_barrier, stage issued AFTER the barrier. (round-4, measured 43us)
// ---------------------------------------------------------------------------
__global__ __launch_bounds__(256) void qkv_scan(
    const ushort* __restrict__ Xq16, const ushort* __restrict__ Xs16,
    const ushort* __restrict__ WT,
    const float* __restrict__ bq, const float* __restrict__ bk,
    const float* __restrict__ bv,
    ushort* __restrict__ qo, ushort* __restrict__ ko, ushort* __restrict__ vo,
    float* __restrict__ sumsq,
    const int* __restrict__ deg, int* __restrict__ offsets)
{
    __shared__ ushort As[3][128 * 32];
    __shared__ ushort Bs[3][128 * 32];
    __shared__ float wred[4];
    __shared__ int part[256];

    const int id = blockIdx.x;
    const int t = threadIdx.x;

    if (id == 1536) {   // exclusive scan of deg -> offsets, 128 elems/thread
        const int base = t * 128;
        int s = 0;
        for (int i = 0; i < 128; ++i) s += deg[base + i];
        part[t] = s;
        __syncthreads();
        for (int off = 1; off < 256; off <<= 1) {
            int a = part[t];
            int b2 = (t >= off) ? part[t - off] : 0;
            __syncthreads();
            part[t] = a + b2;
            __syncthreads();
        }
        int run = (t == 0) ? 0 : part[t - 1];
        for (int i = 0; i < 128; ++i) { offsets[base + i] = run; run += deg[base + i]; }
        if (t == 255) offsets[NN] = run;
        return;
    }

    const int vv = (id & 7) * 192 + (id >> 3);   // XCD-contiguous row-groups
    const int rt = vv / 6, ct = vv % 6;
    const int wsel = ct >> 1;                    // 0:q 1:k 2:v
    const ushort* A16 = (wsel == 0) ? Xq16 : Xs16;
    const ushort* W   = WT + (size_t)wsel * 65536;
    const float* bias = (wsel == 0) ? bq : (wsel == 1) ? bk : bv;
    ushort* C         = (wsel == 0) ? qo : (wsel == 1) ? ko : vo;
    const int row0 = rt * 128;
    const int col0 = (ct & 1) * 128;

    const int l = t & 63, w = t >> 6;
    const int fr = l & 15, q4 = l >> 4;
    const int wr = (w & 1) * 64, wc = (w >> 1) * 64;

    // staging: per wave, 64 lanes x 16B contiguous LDS
    const int srow = (w << 4) + (l >> 2);        // 0..63 within 64-row half
    const int scol = (l & 3) << 3;               // 0,8,16,24
    const ushort* ga = &A16[(size_t)(row0 + srow) * INF + scol];
    const ushort* gb = &W  [(size_t)(col0 + srow) * INF + scol];
    const int lbase = (w << 9);                  // wave-uniform ushort offset

    f32x4 acc[4][4] = {};

#define QKV_STAGE(bufi, k0) \
    GLD16(ga + (k0),            &As[bufi][lbase]); \
    GLD16(ga + (k0) + 64 * INF, &As[bufi][2048 + lbase]); \
    GLD16(gb + (k0),            &Bs[bufi][lbase]); \
    GLD16(gb + (k0) + 64 * INF, &Bs[bufi][2048 + lbase]);

#define QKV_COMPUTE(bufi) { \
    const int kg = q4 * 8; \
    s16x8 af[4], bfr[4]; \
    _Pragma("unroll") \
    for (int i = 0; i < 4; ++i) \
        af[i] = *(const s16x8*)&As[bufi][(wr + i * 16 + fr) * 32 + kg]; \
    _Pragma("unroll") \
    for (int j = 0; j < 4; ++j) \
        bfr[j] = *(const s16x8*)&Bs[bufi][(wc + j * 16 + fr) * 32 + kg]; \
    _Pragma("unroll") \
    for (int i = 0; i < 4; ++i) \
    _Pragma("unroll") \
        for (int j = 0; j < 4; ++j) \
            acc[i][j] = __builtin_amdgcn_mfma_f32_16x16x32_bf16( \
                af[i], bfr[j], acc[i][j], 0, 0, 0); }

#define WAIT4 asm volatile("s_waitcnt vmcnt(4)" ::: "memory")
#define WAIT0 asm volatile("s_waitcnt vmcnt(0)" ::: "memory")
#define BAR   __builtin_amdgcn_s_barrier()

    // prologue: buffers 0 and 1 in flight
    QKV_STAGE(0, 0)
    QKV_STAGE(1, 32)

    WAIT4; BAR; QKV_STAGE(2,  64) QKV_COMPUTE(0)   // it0
    WAIT4; BAR; QKV_STAGE(0,  96) QKV_COMPUTE(1)   // it1
    WAIT4; BAR; QKV_STAGE(1, 128) QKV_COMPUTE(2)   // it2
    WAIT4; BAR; QKV_STAGE(2, 160) QKV_COMPUTE(0)   // it3
    WAIT4; BAR; QKV_STAGE(0, 192) QKV_COMPUTE(1)   // it4
    WAIT4; BAR; QKV_STAGE(1, 224) QKV_COMPUTE(2)   // it5
    WAIT4; BAR;                   QKV_COMPUTE(0)   // it6
    WAIT0; BAR;                   QKV_COMPUTE(1)   // it7

    float loc = 0.f;
#pragma unroll
    for (int j = 0; j < 4; ++j) {
        const int colg = col0 + wc + j * 16 + fr;
        const float bj = bias[colg];
#pragma unroll
        for (int i = 0; i < 4; ++i) {
            const int rowg = row0 + wr + i * 16 + q4 * 4;
#pragma unroll
            for (int m = 0; m < 4; ++m) {
                float cv = acc[i][j][m] + bj;
                loc += cv * cv;
                C[(size_t)(rowg + m) * HD + colg] = f2bf(cv);
            }
        }
    }
    if (wsel < 2) {
#pragma unroll
        for (int off = 32; off > 0; off >>= 1) loc += __shfl_down(loc, off, 64);
        if (l == 0) wred[w] = loc;
        __syncthreads();
        if (t == 0) atomicAdd(&sumsq[wsel], wred[0] + wred[1] + wred[2] + wred[3]);
    }
}

// ---------------------------------------------------------------------------
// K3: kv_mfma (blocks 0..1023) ∪ vbar (blocks 1024..3071, 4 elems/thread).
// kv parts stored transposed [dv][dk] for attn's B-operand layout.
// ---------------------------------------------------------------------------
#define KVP 136
__global__ __launch_bounds__(256) void kv_vbar(
    const ushort* __restrict__ k16, const ushort* __restrict__ v16,
    float* __restrict__ kv_p, float* __restrict__ ksum_p, float* __restrict__ vsum_p,
    float* __restrict__ vbar)
{
    __shared__ ushort kT[64 * KVP];
    __shared__ ushort vT[64 * KVP];
    const int bid = blockIdx.x;
    const int t = threadIdx.x;

    if (bid >= 1024) {   // vbar: mean over heads
        const int idx = (bid - 1024) * 1024 + t * 4;
        const int n = idx >> 6, d0 = idx & 63;
        const ushort* vr = &v16[(size_t)n * HD + d0];
        float4 o;
        float* op = (float*)&o;
#pragma unroll
        for (int j = 0; j < 4; ++j)
            op[j] = 0.25f * (bf2f(vr[j]) + bf2f(vr[64 + j]) +
                             bf2f(vr[128 + j]) + bf2f(vr[192 + j]));
        *(float4*)&vbar[idx] = o;
        return;
    }

    const int h = bid & 3, b = (bid >> 2) & 63, z = bid >> 8;
    const int l = t & 63, w = t >> 6;
    const size_t base = (size_t)b * MM * HD + (size_t)h * DD;
    const int m0 = z * 128;

    {
        const int mat = t >> 7;
        const int u = t & 63;
        const int dhalf = (t >> 6) & 1;
        const int r0 = 2 * u;
        const int d0 = dhalf * 32;
        const ushort* src = mat ? v16 : k16;
        ushort* dst = mat ? vT : kT;
        const ushort* p0 = &src[base + (size_t)(m0 + r0) * HD + d0];
        const ushort* p1 = p0 + HD;
        u16x8 ra[4], rb[4];
#pragma unroll
        for (int i = 0; i < 4; ++i) ra[i] = *(const u16x8*)(p0 + 8 * i);
#pragma unroll
        for (int i = 0; i < 4; ++i) rb[i] = *(const u16x8*)(p1 + 8 * i);
#pragma unroll
        for (int i = 0; i < 4; ++i)
#pragma unroll
            for (int jj = 0; jj < 8; ++jj) {
                const int d = d0 + 8 * i + jj;
                uint pk = (uint)ra[i][jj] | ((uint)rb[i][jj] << 16);
                *(uint*)&dst[d * KVP + r0] = pk;
            }
    }
    __syncthreads();

    const int fr = l & 15, q4 = l >> 4, kg = q4 * 8;
    const int wr2 = (w & 1) * 32, wc2 = (w >> 1) * 32;
    s16x8 ones;
#pragma unroll
    for (int i = 0; i < 8; ++i) ones[i] = (short)0x3F80;

    f32x4 acc[2][2] = {};
    f32x4 aks[2] = {};
    f32x4 avs[2] = {};
#pragma unroll
    for (int s = 0; s < 4; ++s) {
        const int mo = s * 32 + kg;
        s16x8 af[2], bf[2];
        af[0] = *(const s16x8*)&kT[(wr2 + fr) * KVP + mo];
        af[1] = *(const s16x8*)&kT[(wr2 + 16 + fr) * KVP + mo];
        bf[0] = *(const s16x8*)&vT[(wc2 + fr) * KVP + mo];
        bf[1] = *(const s16x8*)&vT[(wc2 + 16 + fr) * KVP + mo];
#pragma unroll
        for (int il = 0; il < 2; ++il)
#pragma unroll
            for (int jl = 0; jl < 2; ++jl)
                acc[il][jl] = __builtin_amdgcn_mfma_f32_16x16x32_bf16(
                    af[il], bf[jl], acc[il][jl], 0, 0, 0);
#pragma unroll
        for (int il = 0; il < 2; ++il)
            aks[il] = __builtin_amdgcn_mfma_f32_16x16x32_bf16(
                af[il], ones, aks[il], 0, 0, 0);
#pragma unroll
        for (int jl = 0; jl < 2; ++jl)
            avs[jl] = __builtin_amdgcn_mfma_f32_16x16x32_bf16(
                ones, bf[jl], avs[jl], 0, 0, 0);
    }

    float* kvb = &kv_p[(((size_t)b * HH + h) * 4 + z) * 4096];
#pragma unroll
    for (int jl = 0; jl < 2; ++jl) {
        const int dv = wc2 + 16 * jl + fr;
#pragma unroll
        for (int il = 0; il < 2; ++il) {
            const int dk = wr2 + 16 * il + q4 * 4;
            *(f32x4*)&kvb[(size_t)dv * 64 + dk] = acc[il][jl];
        }
    }
    float* ksb = &ksum_p[(((size_t)b * HH + h) * 4 + z) * 64];
    float* vsb = &vsum_p[(((size_t)b * HH + h) * 4 + z) * 64];
    if (wc2 == 0 && fr == 0) {
#pragma unroll
        for (int il = 0; il < 2; ++il)
#pragma unroll
            for (int m = 0; m < 4; ++m)
                ksb[wr2 + 16 * il + q4 * 4 + m] = aks[il][m];
    }
    if (wr2 == 0 && l < 16) {
        vsb[wc2 + l]      = avs[0][0];
        vsb[wc2 + 16 + l] = avs[1][0];
    }
}

// ---------------------------------------------------------------------------
// K4: kv_red (blocks 0..1023) ∪ sumred (1024..1151) ∪ bucket (1152..3199).
// ---------------------------------------------------------------------------
__global__ __launch_bounds__(256) void red_bucket(
    const float* __restrict__ kv_p, const float* __restrict__ ksum_p,
    const float* __restrict__ vsum_p,
    ushort* __restrict__ kv16, float* __restrict__ ksum_f, float* __restrict__ vsum_f,
    const int* __restrict__ ei, const float* __restrict__ ew,
    const int* __restrict__ deg, const int* __restrict__ offsets,
    int* __restrict__ cursor, int2* __restrict__ pairbuf)
{
    const int bid = blockIdx.x;
    const int t = threadIdx.x;

    if (bid < 1024) {          // kv_red: 4 outputs/thread
        const int o4 = bid * 1024 + t * 4;
        const int bh = o4 >> 12, off = o4 & 4095;
        const float* p = &kv_p[(size_t)bh * 16384 + off];
        float4 s0 = *(const float4*)p;
        float4 s1 = *(const float4*)(p + 4096);
        float4 s2 = *(const float4*)(p + 8192);
        float4 s3 = *(const float4*)(p + 12288);
        const float r0 = s0.x + s1.x + s2.x + s3.x;
        const float r1 = s0.y + s1.y + s2.y + s3.y;
        const float r2 = s0.z + s1.z + s2.z + s3.z;
        const float r3 = s0.w + s1.w + s2.w + s3.w;
        uint2 pk = make_uint2(pkbf(r0, r1), pkbf(r2, r3));
        *(uint2*)&kv16[(size_t)bh * 4096 + off] = pk;
    } else if (bid < 1152) {   // ksum/vsum reduce
        const int o = (bid - 1024) * 256 + t;    // 0..32767
        const float* src = (o < 16384) ? ksum_p : vsum_p;
        float* dst = (o < 16384) ? ksum_f : vsum_f;
        const int oo = o & 16383;
        const int bh = oo >> 6, d = oo & 63;
        const float* p = &src[(size_t)bh * 256 + d];
        dst[oo] = p[0] + p[64] + p[128] + p[192];
    } else {                   // bucket
        const int e = (bid - 1152) * 256 + t;
        const int row = ei[e], col = ei[EE + e];
        const long long prod = (long long)deg[row] * (long long)deg[col];
        float val = 0.f;
        if (prod > 0) val = ew[e] * __frsqrt_rn((float)prod);
        const int pos = atomicAdd(&cursor[col], 1);
        pairbuf[offsets[col] + pos] = make_int2(row, __float_as_int(val));
    }
}

// ---------------------------------------------------------------------------
// K5: attn via MFMA. All 4 heads' KV + sums staged once; all 256
// denominators in one phase (thread = (row, head)); head loop is pure
// MFMA+epilogue with zero barriers. 12 barriers/block -> 2.
// ---------------------------------------------------------------------------
#define AKP 72
__global__ __launch_bounds__(256) void attn_mfma(
    const ushort* __restrict__ q16, const ushort* __restrict__ kv16,
    const float* __restrict__ ksum_f, const float* __restrict__ vsum_f,
    const float* __restrict__ sumsq,
    const int* __restrict__ n_nodes, float* __restrict__ out)
{
    const int b = blockIdx.y;
    const int m0 = blockIdx.x * 64;
    const int t = threadIdx.x;
    const int l = t & 63, w = t >> 6;
    const int fr = l & 15, q4 = l >> 4;
    const int wn = (w & 1) * 32, wd = (w >> 1) * 32;

    __shared__ ushort kvbf[HH][64 * AKP];
    __shared__ float ksum_l[HH][64], vsum_l[HH][64], denom_l[HH][64];

    const float nn = (float)n_nodes[b];
    const float inv = 1.0f / (sqrtf(sumsq[0]) * sqrtf(sumsq[1]));

    {   // stage all heads: bf16 KV [dv][dk] + ksum/vsum
        const int dv = t >> 2, dk0 = (t & 3) * 16;
#pragma unroll
        for (int h = 0; h < HH; ++h) {
            const ushort* kvg = &kv16[((size_t)(b * HH + h)) * 4096 + dv * 64 + dk0];
            *(uint4*)&kvbf[h][dv * AKP + dk0]     = *(const uint4*)kvg;
            *(uint4*)&kvbf[h][dv * AKP + dk0 + 8] = *(const uint4*)(kvg + 8);
        }
        const int hh = t >> 6, dd = t & 63;
        ksum_l[hh][dd] = ksum_f[((size_t)(b * HH + hh)) * 64 + dd];
        vsum_l[hh][dd] = vsum_f[((size_t)(b * HH + hh)) * 64 + dd];
    }
    __syncthreads();

    {   // denominators, all heads at once: thread = (row r, head hh)
        const int r = t & 63, hh = t >> 6;
        const ushort* qr = &q16[((size_t)(b * MM + m0 + r)) * HD + hh * DD];
        float dsum = 0.f;
#pragma unroll
        for (int c = 0; c < 8; ++c) {
            u16x8 qv = *(const u16x8*)(qr + 8 * c);
#pragma unroll
            for (int j2 = 0; j2 < 8; ++j2)
                dsum += bf2f(qv[j2]) * ksum_l[hh][8 * c + j2];
        }
        denom_l[hh][r] = nn + inv * dsum;
    }
    __syncthreads();

    f32x4 acco[2][2] = {};
#pragma unroll
    for (int h = 0; h < HH; ++h) {
        f32x4 pacc[2][2] = {};
#pragma unroll
        for (int kx = 0; kx < 2; ++kx) {
            const int k0 = kx * 32;
            s16x8 af[2], bfr[2];
#pragma unroll
            for (int il = 0; il < 2; ++il)
                af[il] = *(const s16x8*)&q16[
                    ((size_t)(b * MM + m0 + wn + 16 * il + fr)) * HD + h * DD + k0 + q4 * 8];
#pragma unroll
            for (int jl = 0; jl < 2; ++jl)
                bfr[jl] = *(const s16x8*)&kvbf[h][(wd + 16 * jl + fr) * AKP + k0 + q4 * 8];
#pragma unroll
            for (int il = 0; il < 2; ++il)
#pragma unroll
                for (int jl = 0; jl < 2; ++jl)
                    pacc[il][jl] = __builtin_amdgcn_mfma_f32_16x16x32_bf16(
                        af[il], bfr[jl], pacc[il][jl], 0, 0, 0);
        }
#pragma unroll
        for (int il = 0; il < 2; ++il)
#pragma unroll
            for (int m = 0; m < 4; ++m) {
                const float rden = 0.25f / denom_l[h][wn + 16 * il + q4 * 4 + m];
#pragma unroll
                for (int jl = 0; jl < 2; ++jl) {
                    const int d = wd + 16 * jl + fr;
                    acco[il][jl][m] += (inv * pacc[il][jl][m] + vsum_l[h][d]) * rden;
                }
            }
    }

#pragma unroll
    for (int il = 0; il < 2; ++il)
#pragma unroll
        for (int m = 0; m < 4; ++m) {
            const size_t node = (size_t)b * MM + m0 + wn + 16 * il + q4 * 4 + m;
#pragma unroll
            for (int jl = 0; jl < 2; ++jl)
                out[node * DD + wd + 16 * jl + fr] = acco[il][jl][m];
        }
}

// ---------------------------------------------------------------------------
// K6: GCN gather, 32 threads/node (2 groups of 16 split even/odd edges,
// combine via shfl_xor 16). Serial gather chain halved.
// ---------------------------------------------------------------------------
__global__ __launch_bounds__(256) void gcn_gather(
    const int* __restrict__ offsets, const int2* __restrict__ pairbuf,
    const float* __restrict__ vbar, float* __restrict__ out)
{
    const int t = blockIdx.x * 256 + threadIdx.x;   // NN*32 threads
    const int n = t >> 5;
    const int g = t & 31;
    const int d4 = (g & 15) << 2;
    const int grp = g >> 4;
    const int s = offsets[n], e = offsets[n + 1];
    float ax = 0.f, ay = 0.f, az = 0.f, aw = 0.f;
    int i = s + grp;
    for (; i + 2 < e; i += 4) {   // two edges (stride-2 within group)
        const int2 p0 = pairbuf[i], p1 = pairbuf[i + 2];
        const float w0 = __int_as_float(p0.y), w1 = __int_as_float(p1.y);
        const float4 v0 = *(const float4*)&vbar[(size_t)p0.x * DD + d4];
        const float4 v1 = *(const float4*)&vbar[(size_t)p1.x * DD + d4];
        ax += w0 * v0.x + w1 * v1.x;
        ay += w0 * v0.y + w1 * v1.y;
        az += w0 * v0.z + w1 * v1.z;
        aw += w0 * v0.w + w1 * v1.w;
    }
    if (i < e) {
        const int2 p = pairbuf[i];
        const float wv = __int_as_float(p.y);
        const float4 v = *(const float4*)&vbar[(size_t)p.x * DD + d4];
        ax += wv * v.x; ay += wv * v.y; az += wv * v.z; aw += wv * v.w;
    }
    ax += __shfl_xor(ax, 16, 64);
    ay += __shfl_xor(ay, 16, 64);
    az += __shfl_xor(az, 16, 64);
    aw += __shfl_xor(aw, 16, 64);
    if (grp == 0) {
        float4 o = *(float4*)&out[(size_t)n * DD + d4];
        o.x += ax; o.y += ay; o.z += az; o.w += aw;
        *(float4*)&out[(size_t)n * DD + d4] = o;
    }
}

// ---------------------------------------------------------------------------
extern "C" void kernel_launch(void* const* d_in, const int* in_sizes, int n_in,
                              void* d_out, int out_size, void* d_ws, size_t ws_size,
                              hipStream_t stream)
{
    (void)in_sizes; (void)n_in; (void)out_size; (void)ws_size;
    const float* Xq = (const float*)d_in[0];
    const float* Xs = (const float*)d_in[1];
    const float* ew = (const float*)d_in[2];
    const float* Wq = (const float*)d_in[3];
    const float* bq = (const float*)d_in[4];
    const float* Wk = (const float*)d_in[5];
    const float* bk = (const float*)d_in[6];
    const float* Wv = (const float*)d_in[7];
    const float* bv = (const float*)d_in[8];
    const int* n_nodes = (const int*)d_in[9];
    const int* ei = (const int*)d_in[10];
    float* out = (float*)d_out;
    float* ws  = (float*)d_ws;

    // workspace layout (float units); q/k/v bf16
    const size_t SZ_QKV   = (size_t)NN * HD / 2;       // 4194304 each
    const size_t OFF_Q    = 0;
    const size_t OFF_K    = SZ_QKV;
    const size_t OFF_V    = SZ_QKV * 2;
    const size_t OFF_SS   = SZ_QKV * 3;                // 16 floats (zeroed)
    const size_t OFF_DEG  = OFF_SS + 16;               // NN ints (zeroed)
    const size_t OFF_CUR  = OFF_DEG + NN;              // NN ints (zeroed)
    const size_t OFF_WT   = OFF_CUR + NN;              // 3*65536 ushorts
    const size_t OFF_OFFS = OFF_WT + 3 * 65536 / 2;    // NN+1 (+pad)
    const size_t OFF_UNI  = OFF_OFFS + NN + 16;
    // phase 1 (prep + qkv_scan): Xq16, Xs16 bf16 copies of inputs
    const size_t OFF_XQ16 = OFF_UNI;                   // XSZ/2 = 4194304
    const size_t OFF_XS16 = OFF_UNI + XSZ / 2;         // 4194304
    // phase 2 (kv_vbar onward) — Xq16/Xs16 dead, region reused:
    const size_t OFF_KV   = OFF_UNI;                                  // 4194304
    const size_t OFF_KSP  = OFF_KV + (size_t)BB * HH * 4 * 4096;      // 65536
    const size_t OFF_VSP  = OFF_KSP + (size_t)BB * HH * 4 * 64;       // 65536
    const size_t OFF_KV16 = OFF_VSP + (size_t)BB * HH * 4 * 64;       // 524288
    const size_t OFF_KSF  = OFF_KV16 + (size_t)BB * HH * 4096 / 2;    // 16384
    const size_t OFF_VSF  = OFF_KSF + (size_t)BB * HH * 64;           // 16384
    const size_t OFF_PAIR = OFF_VSF + (size_t)BB * HH * 64;           // 1048576
    const size_t OFF_VBAR = OFF_PAIR + 2 * (size_t)EE;                // 2097152
    // phase-2 extent fits inside phase-1 union; total ws ≈ 85 MB

    ushort* q16   = (ushort*)(ws + OFF_Q);
    ushort* k16   = (ushort*)(ws + OFF_K);
    ushort* v16   = (ushort*)(ws + OFF_V);
    float* sumsq  = ws + OFF_SS;
    int*   deg    = (int*)(ws + OFF_DEG);
    int*   cursor = (int*)(ws + OFF_CUR);
    ushort* WT    = (ushort*)(ws + OFF_WT);
    int*   offs   = (int*)(ws + OFF_OFFS);
    ushort* xq16  = (ushort*)(ws + OFF_XQ16);
    ushort* xs16  = (ushort*)(ws + OFF_XS16);
    float* kv_p   = ws + OFF_KV;
    float* ksum_p = ws + OFF_KSP;
    float* vsum_p = ws + OFF_VSP;
    ushort* kv16  = (ushort*)(ws + OFF_KV16);
    float* ksum_f = ws + OFF_KSF;
    float* vsum_f = ws + OFF_VSF;
    int2*  pairb  = (int2*)(ws + OFF_PAIR);
    float* vbar   = ws + OFF_VBAR;

    // zero sumsq + deg + cursor (contiguous)
    hipMemsetAsync(sumsq, 0, (16 + 2 * NN) * sizeof(float), stream);
    prep_kernel<<<11008, 256, 0, stream>>>(Wq, Wk, Wv, WT, ei, deg, Xq, Xs, xq16, xs16);
    qkv_scan<<<1537, 256, 0, stream>>>(
        xq16, xs16, WT, bq, bk, bv, q16, k16, v16, sumsq, deg, offs);
    kv_vbar<<<3072, 256, 0, stream>>>(k16, v16, kv_p, ksum_p, vsum_p, vbar);
    red_bucket<<<3200, 256, 0, stream>>>(
        kv_p, ksum_p, vsum_p, kv16, ksum_f, vsum_f,
        ei, ew, deg, offs, cursor, pairb);
    attn_mfma<<<dim3(MM / 64, BB), 256, 0, stream>>>(
        q16, kv16, ksum_f, vsum_f, sumsq, n_nodes, out);
    gcn_gather<<<(NN * 32) / 256, 256, 0, stream>>>(offs, pairb, vbar, out);
}

// Round 6
// 250.259 us; speedup vs baseline: 1.1838x; 1.0211x over previous
//
#include <hip/hip_runtime.h>
#include <hip/hip_bf16.h>

#define NN 32768   // nodes
#define BB 64      // graphs
#define MM 512     // nodes per graph
#define HH 4       // heads
#define DD 64      // head dim
#define INF 256    // input features
#define HD 256     // H*D
#define EE 524288  // edges
#define XSZ 8388608  // NN*INF elements per X matrix

typedef unsigned short ushort;
typedef unsigned int uint;
typedef short s16x8 __attribute__((ext_vector_type(8)));
typedef ushort u16x8 __attribute__((ext_vector_type(8)));
typedef float f32x4 __attribute__((ext_vector_type(4)));

__device__ __forceinline__ ushort f2bf(float f) {
    uint u = __float_as_uint(f);
    return (ushort)((u + 0x7fffu + ((u >> 16) & 1u)) >> 16);
}
__device__ __forceinline__ float bf2f(ushort u) {
    return __uint_as_float((uint)u << 16);
}
__device__ __forceinline__ uint pkbf(float x, float y) {
    __hip_bfloat162 h = __float22bfloat162_rn(make_float2(x, y));
    return *(uint*)&h;
}

#define GLD16(gp, lp) __builtin_amdgcn_global_load_lds( \
    (const __attribute__((address_space(1))) void*)(gp), \
    (__attribute__((address_space(3))) void*)(lp), 16, 0, 0)

// ---------------------------------------------------------------------------
// K1: convert_w (blocks 0..767) ∪ deg histogram (blocks 768..2815) ∪
//     X f32->bf16 convert (blocks 2816..11007).
// ---------------------------------------------------------------------------
__global__ __launch_bounds__(256) void prep_kernel(
    const float* __restrict__ Wq, const float* __restrict__ Wk,
    const float* __restrict__ Wv, ushort* __restrict__ WT,
    const int* __restrict__ ei, int* __restrict__ deg,
    const float* __restrict__ Xq, const float* __restrict__ Xs,
    ushort* __restrict__ xq16, ushort* __restrict__ xs16)
{
    const int bid = blockIdx.x;
    if (bid < 768) {
        const int id = bid * 256 + threadIdx.x;      // 3*65536
        const int mat = id >> 16, rem = id & 65535;
        const int n = rem >> 8, kk = rem & 255;
        const float* W = (mat == 0) ? Wq : (mat == 1) ? Wk : Wv;
        WT[id] = f2bf(W[kk * 256 + n]);              // WT[mat][n][kk]
    } else if (bid < 2816) {
        const int e = (bid - 768) * 256 + threadIdx.x;   // EE total
        atomicAdd(&deg[ei[EE + e]], 1);
    } else {
        const size_t id = (size_t)(bid - 2816) * 256 + threadIdx.x;
        const size_t o8 = id * 8;                    // 8 floats / thread
        const float* src; ushort* dst; size_t o;
        if (o8 < XSZ) { src = Xq; dst = xq16; o = o8; }
        else          { src = Xs; dst = xs16; o = o8 - XSZ; }
        const float4 f0 = *(const float4*)(src + o);
        const float4 f1 = *(const float4*)(src + o + 4);
        u16x8 r;
        r[0] = f2bf(f0.x); r[1] = f2bf(f0.y); r[2] = f2bf(f0.z); r[3] = f2bf(f0.w);
        r[4] = f2bf(f1.x); r[5] = f2bf(f1.y); r[6] = f2bf(f1.z); r[7] = f2bf(f1.w);
        *(u16x8*)(dst + o) = r;
    }
}

// ---------------------------------------------------------------------------
// K2: qkv GEMM (blocks 0..1535) ∪ scan (block 1536).
// T4-pipelined: 3 LDS buffers, counted s_waitcnt vmcnt(4) before raw
// s_barrier, stage issued AFTER the barrier. (round-4, measured 43us)
// ---------------------------------------------------------------------------
__global__ __launch_bounds__(256) void qkv_scan(
    const ushort* __restrict__ Xq16, const ushort* __restrict__ Xs16,
    const ushort* __restrict__ WT,
    const float* __restrict__ bq, const float* __restrict__ bk,
    const float* __restrict__ bv,
    ushort* __restrict__ qo, ushort* __restrict__ ko, ushort* __restrict__ vo,
    float* __restrict__ sumsq,
    const int* __restrict__ deg, int* __restrict__ offsets)
{
    __shared__ ushort As[3][128 * 32];
    __shared__ ushort Bs[3][128 * 32];
    __shared__ float wred[4];
    __shared__ int part[256];

    const int id = blockIdx.x;
    const int t = threadIdx.x;

    if (id == 1536) {   // exclusive scan of deg -> offsets, 128 elems/thread
        const int base = t * 128;
        int s = 0;
        for (int i = 0; i < 128; ++i) s += deg[base + i];
        part[t] = s;
        __syncthreads();
        for (int off = 1; off < 256; off <<= 1) {
            int a = part[t];
            int b2 = (t >= off) ? part[t - off] : 0;
            __syncthreads();
            part[t] = a + b2;
            __syncthreads();
        }
        int run = (t == 0) ? 0 : part[t - 1];
        for (int i = 0; i < 128; ++i) { offsets[base + i] = run; run += deg[base + i]; }
        if (t == 255) offsets[NN] = run;
        return;
    }

    const int vv = (id & 7) * 192 + (id >> 3);   // XCD-contiguous row-groups
    const int rt = vv / 6, ct = vv % 6;
    const int wsel = ct >> 1;                    // 0:q 1:k 2:v
    const ushort* A16 = (wsel == 0) ? Xq16 : Xs16;
    const ushort* W   = WT + (size_t)wsel * 65536;
    const float* bias = (wsel == 0) ? bq : (wsel == 1) ? bk : bv;
    ushort* C         = (wsel == 0) ? qo : (wsel == 1) ? ko : vo;
    const int row0 = rt * 128;
    const int col0 = (ct & 1) * 128;

    const int l = t & 63, w = t >> 6;
    const int fr = l & 15, q4 = l >> 4;
    const int wr = (w & 1) * 64, wc = (w >> 1) * 64;

    // staging: per wave, 64 lanes x 16B contiguous LDS
    const int srow = (w << 4) + (l >> 2);        // 0..63 within 64-row half
    const int scol = (l & 3) << 3;               // 0,8,16,24
    const ushort* ga = &A16[(size_t)(row0 + srow) * INF + scol];
    const ushort* gb = &W  [(size_t)(col0 + srow) * INF + scol];
    const int lbase = (w << 9);                  // wave-uniform ushort offset

    f32x4 acc[4][4] = {};

#define QKV_STAGE(bufi, k0) \
    GLD16(ga + (k0),            &As[bufi][lbase]); \
    GLD16(ga + (k0) + 64 * INF, &As[bufi][2048 + lbase]); \
    GLD16(gb + (k0),            &Bs[bufi][lbase]); \
    GLD16(gb + (k0) + 64 * INF, &Bs[bufi][2048 + lbase]);

#define QKV_COMPUTE(bufi) { \
    const int kg = q4 * 8; \
    s16x8 af[4], bfr[4]; \
    _Pragma("unroll") \
    for (int i = 0; i < 4; ++i) \
        af[i] = *(const s16x8*)&As[bufi][(wr + i * 16 + fr) * 32 + kg]; \
    _Pragma("unroll") \
    for (int j = 0; j < 4; ++j) \
        bfr[j] = *(const s16x8*)&Bs[bufi][(wc + j * 16 + fr) * 32 + kg]; \
    _Pragma("unroll") \
    for (int i = 0; i < 4; ++i) \
    _Pragma("unroll") \
        for (int j = 0; j < 4; ++j) \
            acc[i][j] = __builtin_amdgcn_mfma_f32_16x16x32_bf16( \
                af[i], bfr[j], acc[i][j], 0, 0, 0); }

#define WAIT4 asm volatile("s_waitcnt vmcnt(4)" ::: "memory")
#define WAIT0 asm volatile("s_waitcnt vmcnt(0)" ::: "memory")
#define BAR   __builtin_amdgcn_s_barrier()

    // prologue: buffers 0 and 1 in flight
    QKV_STAGE(0, 0)
    QKV_STAGE(1, 32)

    WAIT4; BAR; QKV_STAGE(2,  64) QKV_COMPUTE(0)   // it0
    WAIT4; BAR; QKV_STAGE(0,  96) QKV_COMPUTE(1)   // it1
    WAIT4; BAR; QKV_STAGE(1, 128) QKV_COMPUTE(2)   // it2
    WAIT4; BAR; QKV_STAGE(2, 160) QKV_COMPUTE(0)   // it3
    WAIT4; BAR; QKV_STAGE(0, 192) QKV_COMPUTE(1)   // it4
    WAIT4; BAR; QKV_STAGE(1, 224) QKV_COMPUTE(2)   // it5
    WAIT4; BAR;                   QKV_COMPUTE(0)   // it6
    WAIT0; BAR;                   QKV_COMPUTE(1)   // it7

    float loc = 0.f;
#pragma unroll
    for (int j = 0; j < 4; ++j) {
        const int colg = col0 + wc + j * 16 + fr;
        const float bj = bias[colg];
#pragma unroll
        for (int i = 0; i < 4; ++i) {
            const int rowg = row0 + wr + i * 16 + q4 * 4;
#pragma unroll
            for (int m = 0; m < 4; ++m) {
                float cv = acc[i][j][m] + bj;
                loc += cv * cv;
                C[(size_t)(rowg + m) * HD + colg] = f2bf(cv);
            }
        }
    }
    if (wsel < 2) {
#pragma unroll
        for (int off = 32; off > 0; off >>= 1) loc += __shfl_down(loc, off, 64);
        if (l == 0) wred[w] = loc;
        __syncthreads();
        if (t == 0) atomicAdd(&sumsq[wsel], wred[0] + wred[1] + wred[2] + wred[3]);
    }
}

// ---------------------------------------------------------------------------
// K3: kv full-pass MFMA (blocks 0..255: one (b,h) each, 4 chunks of 128
// rows accumulated in-register; writes kv16 bf16 + ksum_f/vsum_f DIRECTLY
// — kv_p partials and the red dispatch are eliminated) ∪ vbar (blocks
// 256..2303) ∪ bucket (blocks 2304..4351, overlaps the MFMA blocks).
// ---------------------------------------------------------------------------
#define KVP 136
__global__ __launch_bounds__(256) void kv_vbar_bucket(
    const ushort* __restrict__ k16, const ushort* __restrict__ v16,
    ushort* __restrict__ kv16, float* __restrict__ ksum_f, float* __restrict__ vsum_f,
    float* __restrict__ vbar,
    const int* __restrict__ ei, const float* __restrict__ ew,
    const int* __restrict__ deg, const int* __restrict__ offsets,
    int* __restrict__ cursor, int2* __restrict__ pairbuf)
{
    __shared__ ushort kT[64 * KVP];
    __shared__ ushort vT[64 * KVP];
    const int bid = blockIdx.x;
    const int t = threadIdx.x;

    if (bid >= 2304) {   // bucket: CSR fill, packed int2 {row, val}
        const int e = (bid - 2304) * 256 + t;
        const int row = ei[e], col = ei[EE + e];
        const long long prod = (long long)deg[row] * (long long)deg[col];
        float val = 0.f;
        if (prod > 0) val = ew[e] * __frsqrt_rn((float)prod);
        const int pos = atomicAdd(&cursor[col], 1);
        pairbuf[offsets[col] + pos] = make_int2(row, __float_as_int(val));
        return;
    }
    if (bid >= 256) {    // vbar: mean over heads
        const int idx = (bid - 256) * 1024 + t * 4;
        const int n = idx >> 6, d0 = idx & 63;
        const ushort* vr = &v16[(size_t)n * HD + d0];
        float4 o;
        float* op = (float*)&o;
#pragma unroll
        for (int j = 0; j < 4; ++j)
            op[j] = 0.25f * (bf2f(vr[j]) + bf2f(vr[64 + j]) +
                             bf2f(vr[128 + j]) + bf2f(vr[192 + j]));
        *(float4*)&vbar[idx] = o;
        return;
    }

    // ---- kv MFMA: one (b,h), all 512 rows ----
    const int h = bid & 3, b = bid >> 2;
    const int l = t & 63, w = t >> 6;
    const size_t base = (size_t)b * MM * HD + (size_t)h * DD;

    const int fr = l & 15, q4 = l >> 4, kg = q4 * 8;
    const int wr2 = (w & 1) * 32, wc2 = (w >> 1) * 32;
    s16x8 ones;
#pragma unroll
    for (int i = 0; i < 8; ++i) ones[i] = (short)0x3F80;

    f32x4 acc[2][2] = {};
    f32x4 aks[2] = {};
    f32x4 avs[2] = {};

    // staging decomposition (constant across chunks)
    const int mat = t >> 7;
    const int u = t & 63;
    const int dhalf = (t >> 6) & 1;
    const int r0 = 2 * u;
    const int d0 = dhalf * 32;
    const ushort* src = mat ? v16 : k16;
    ushort* dst = mat ? vT : kT;

    for (int chunk = 0; chunk < 4; ++chunk) {
        const int m0 = chunk * 128;
        {   // transpose-stage 128 rows x 64 d (2 rows/thread, packed uint)
            const ushort* p0 = &src[base + (size_t)(m0 + r0) * HD + d0];
            const ushort* p1 = p0 + HD;
            u16x8 ra[4], rb[4];
#pragma unroll
            for (int i = 0; i < 4; ++i) ra[i] = *(const u16x8*)(p0 + 8 * i);
#pragma unroll
            for (int i = 0; i < 4; ++i) rb[i] = *(const u16x8*)(p1 + 8 * i);
#pragma unroll
            for (int i = 0; i < 4; ++i)
#pragma unroll
                for (int jj = 0; jj < 8; ++jj) {
                    const int d = d0 + 8 * i + jj;
                    uint pk = (uint)ra[i][jj] | ((uint)rb[i][jj] << 16);
                    *(uint*)&dst[d * KVP + r0] = pk;
                }
        }
        __syncthreads();

#pragma unroll
        for (int s = 0; s < 4; ++s) {
            const int mo = s * 32 + kg;
            s16x8 af[2], bf[2];
            af[0] = *(const s16x8*)&kT[(wr2 + fr) * KVP + mo];
            af[1] = *(const s16x8*)&kT[(wr2 + 16 + fr) * KVP + mo];
            bf[0] = *(const s16x8*)&vT[(wc2 + fr) * KVP + mo];
            bf[1] = *(const s16x8*)&vT[(wc2 + 16 + fr) * KVP + mo];
#pragma unroll
            for (int il = 0; il < 2; ++il)
#pragma unroll
                for (int jl = 0; jl < 2; ++jl)
                    acc[il][jl] = __builtin_amdgcn_mfma_f32_16x16x32_bf16(
                        af[il], bf[jl], acc[il][jl], 0, 0, 0);
#pragma unroll
            for (int il = 0; il < 2; ++il)
                aks[il] = __builtin_amdgcn_mfma_f32_16x16x32_bf16(
                    af[il], ones, aks[il], 0, 0, 0);
#pragma unroll
            for (int jl = 0; jl < 2; ++jl)
                avs[jl] = __builtin_amdgcn_mfma_f32_16x16x32_bf16(
                    ones, bf[jl], avs[jl], 0, 0, 0);
        }
        __syncthreads();   // protect LDS overwrite by next chunk
    }

    // epilogue: kv16 bf16 direct, transposed [dv][dk]
    ushort* kvb = &kv16[((size_t)b * HH + h) * 4096];
#pragma unroll
    for (int jl = 0; jl < 2; ++jl) {
        const int dv = wc2 + 16 * jl + fr;
#pragma unroll
        for (int il = 0; il < 2; ++il) {
            const int dk = wr2 + 16 * il + q4 * 4;
            uint2 pk = make_uint2(pkbf(acc[il][jl][0], acc[il][jl][1]),
                                  pkbf(acc[il][jl][2], acc[il][jl][3]));
            *(uint2*)&kvb[(size_t)dv * 64 + dk] = pk;
        }
    }
    float* ksb = &ksum_f[((size_t)b * HH + h) * 64];
    float* vsb = &vsum_f[((size_t)b * HH + h) * 64];
    if (wc2 == 0 && fr == 0) {
#pragma unroll
        for (int il = 0; il < 2; ++il)
#pragma unroll
            for (int m = 0; m < 4; ++m)
                ksb[wr2 + 16 * il + q4 * 4 + m] = aks[il][m];
    }
    if (wr2 == 0 && l < 16) {
        vsb[wc2 + l]      = avs[0][0];
        vsb[wc2 + 16 + l] = avs[1][0];
    }
}

// ---------------------------------------------------------------------------
// K5: attn via MFMA. All 4 heads' KV + sums staged once; all 256
// denominators in one phase; head loop pure MFMA+epilogue, 2 barriers.
// ---------------------------------------------------------------------------
#define AKP 72
__global__ __launch_bounds__(256) void attn_mfma(
    const ushort* __restrict__ q16, const ushort* __restrict__ kv16,
    const float* __restrict__ ksum_f, const float* __restrict__ vsum_f,
    const float* __restrict__ sumsq,
    const int* __restrict__ n_nodes, float* __restrict__ out)
{
    const int b = blockIdx.y;
    const int m0 = blockIdx.x * 64;
    const int t = threadIdx.x;
    const int l = t & 63, w = t >> 6;
    const int fr = l & 15, q4 = l >> 4;
    const int wn = (w & 1) * 32, wd = (w >> 1) * 32;

    __shared__ ushort kvbf[HH][64 * AKP];
    __shared__ float ksum_l[HH][64], vsum_l[HH][64], denom_l[HH][64];

    const float nn = (float)n_nodes[b];
    const float inv = 1.0f / (sqrtf(sumsq[0]) * sqrtf(sumsq[1]));

    {   // stage all heads: bf16 KV [dv][dk] + ksum/vsum
        const int dv = t >> 2, dk0 = (t & 3) * 16;
#pragma unroll
        for (int h = 0; h < HH; ++h) {
            const ushort* kvg = &kv16[((size_t)(b * HH + h)) * 4096 + dv * 64 + dk0];
            *(uint4*)&kvbf[h][dv * AKP + dk0]     = *(const uint4*)kvg;
            *(uint4*)&kvbf[h][dv * AKP + dk0 + 8] = *(const uint4*)(kvg + 8);
        }
        const int hh = t >> 6, dd = t & 63;
        ksum_l[hh][dd] = ksum_f[((size_t)(b * HH + hh)) * 64 + dd];
        vsum_l[hh][dd] = vsum_f[((size_t)(b * HH + hh)) * 64 + dd];
    }
    __syncthreads();

    {   // denominators, all heads at once: thread = (row r, head hh)
        const int r = t & 63, hh = t >> 6;
        const ushort* qr = &q16[((size_t)(b * MM + m0 + r)) * HD + hh * DD];
        float dsum = 0.f;
#pragma unroll
        for (int c = 0; c < 8; ++c) {
            u16x8 qv = *(const u16x8*)(qr + 8 * c);
#pragma unroll
            for (int j2 = 0; j2 < 8; ++j2)
                dsum += bf2f(qv[j2]) * ksum_l[hh][8 * c + j2];
        }
        denom_l[hh][r] = nn + inv * dsum;
    }
    __syncthreads();

    f32x4 acco[2][2] = {};
#pragma unroll
    for (int h = 0; h < HH; ++h) {
        f32x4 pacc[2][2] = {};
#pragma unroll
        for (int kx = 0; kx < 2; ++kx) {
            const int k0 = kx * 32;
            s16x8 af[2], bfr[2];
#pragma unroll
            for (int il = 0; il < 2; ++il)
                af[il] = *(const s16x8*)&q16[
                    ((size_t)(b * MM + m0 + wn + 16 * il + fr)) * HD + h * DD + k0 + q4 * 8];
#pragma unroll
            for (int jl = 0; jl < 2; ++jl)
                bfr[jl] = *(const s16x8*)&kvbf[h][(wd + 16 * jl + fr) * AKP + k0 + q4 * 8];
#pragma unroll
            for (int il = 0; il < 2; ++il)
#pragma unroll
                for (int jl = 0; jl < 2; ++jl)
                    pacc[il][jl] = __builtin_amdgcn_mfma_f32_16x16x32_bf16(
                        af[il], bfr[jl], pacc[il][jl], 0, 0, 0);
        }
#pragma unroll
        for (int il = 0; il < 2; ++il)
#pragma unroll
            for (int m = 0; m < 4; ++m) {
                const float rden = 0.25f / denom_l[h][wn + 16 * il + q4 * 4 + m];
#pragma unroll
                for (int jl = 0; jl < 2; ++jl) {
                    const int d = wd + 16 * jl + fr;
                    acco[il][jl][m] += (inv * pacc[il][jl][m] + vsum_l[h][d]) * rden;
                }
            }
    }

#pragma unroll
    for (int il = 0; il < 2; ++il)
#pragma unroll
        for (int m = 0; m < 4; ++m) {
            const size_t node = (size_t)b * MM + m0 + wn + 16 * il + q4 * 4 + m;
#pragma unroll
            for (int jl = 0; jl < 2; ++jl)
                out[node * DD + wd + 16 * jl + fr] = acco[il][jl][m];
        }
}

// ---------------------------------------------------------------------------
// K6: GCN gather, 32 threads/node (2 groups of 16 split even/odd edges,
// combine via shfl_xor 16).
// ---------------------------------------------------------------------------
__global__ __launch_bounds__(256) void gcn_gather(
    const int* __restrict__ offsets, const int2* __restrict__ pairbuf,
    const float* __restrict__ vbar, float* __restrict__ out)
{
    const int t = blockIdx.x * 256 + threadIdx.x;   // NN*32 threads
    const int n = t >> 5;
    const int g = t & 31;
    const int d4 = (g & 15) << 2;
    const int grp = g >> 4;
    const int s = offsets[n], e = offsets[n + 1];
    float ax = 0.f, ay = 0.f, az = 0.f, aw = 0.f;
    int i = s + grp;
    for (; i + 2 < e; i += 4) {   // two edges (stride-2 within group)
        const int2 p0 = pairbuf[i], p1 = pairbuf[i + 2];
        const float w0 = __int_as_float(p0.y), w1 = __int_as_float(p1.y);
        const float4 v0 = *(const float4*)&vbar[(size_t)p0.x * DD + d4];
        const float4 v1 = *(const float4*)&vbar[(size_t)p1.x * DD + d4];
        ax += w0 * v0.x + w1 * v1.x;
        ay += w0 * v0.y + w1 * v1.y;
        az += w0 * v0.z + w1 * v1.z;
        aw += w0 * v0.w + w1 * v1.w;
    }
    if (i < e) {
        const int2 p = pairbuf[i];
        const float wv = __int_as_float(p.y);
        const float4 v = *(const float4*)&vbar[(size_t)p.x * DD + d4];
        ax += wv * v.x; ay += wv * v.y; az += wv * v.z; aw += wv * v.w;
    }
    ax += __shfl_xor(ax, 16, 64);
    ay += __shfl_xor(ay, 16, 64);
    az += __shfl_xor(az, 16, 64);
    aw += __shfl_xor(aw, 16, 64);
    if (grp == 0) {
        float4 o = *(float4*)&out[(size_t)n * DD + d4];
        o.x += ax; o.y += ay; o.z += az; o.w += aw;
        *(float4*)&out[(size_t)n * DD + d4] = o;
    }
}

// ---------------------------------------------------------------------------
extern "C" void kernel_launch(void* const* d_in, const int* in_sizes, int n_in,
                              void* d_out, int out_size, void* d_ws, size_t ws_size,
                              hipStream_t stream)
{
    (void)in_sizes; (void)n_in; (void)out_size; (void)ws_size;
    const float* Xq = (const float*)d_in[0];
    const float* Xs = (const float*)d_in[1];
    const float* ew = (const float*)d_in[2];
    const float* Wq = (const float*)d_in[3];
    const float* bq = (const float*)d_in[4];
    const float* Wk = (const float*)d_in[5];
    const float* bk = (const float*)d_in[6];
    const float* Wv = (const float*)d_in[7];
    const float* bv = (const float*)d_in[8];
    const int* n_nodes = (const int*)d_in[9];
    const int* ei = (const int*)d_in[10];
    float* out = (float*)d_out;
    float* ws  = (float*)d_ws;

    // workspace layout (float units); q/k/v bf16
    const size_t SZ_QKV   = (size_t)NN * HD / 2;       // 4194304 each
    const size_t OFF_Q    = 0;
    const size_t OFF_K    = SZ_QKV;
    const size_t OFF_V    = SZ_QKV * 2;
    const size_t OFF_SS   = SZ_QKV * 3;                // 16 floats (zeroed)
    const size_t OFF_DEG  = OFF_SS + 16;               // NN ints (zeroed)
    const size_t OFF_CUR  = OFF_DEG + NN;              // NN ints (zeroed)
    const size_t OFF_WT   = OFF_CUR + NN;              // 3*65536 ushorts
    const size_t OFF_OFFS = OFF_WT + 3 * 65536 / 2;    // NN+1 (+pad)
    const size_t OFF_UNI  = OFF_OFFS + NN + 16;
    // phase 1 (prep + qkv_scan): Xq16, Xs16 bf16 copies of inputs
    const size_t OFF_XQ16 = OFF_UNI;                   // XSZ/2 = 4194304
    const size_t OFF_XS16 = OFF_UNI + XSZ / 2;         // 4194304
    // phase 2 (kv_vbar_bucket onward) — Xq16/Xs16 dead, region reused:
    const size_t OFF_KV16 = OFF_UNI;                                  // 524288
    const size_t OFF_KSF  = OFF_KV16 + (size_t)BB * HH * 4096 / 2;    // 16384
    const size_t OFF_VSF  = OFF_KSF + (size_t)BB * HH * 64;           // 16384
    const size_t OFF_PAIR = OFF_VSF + (size_t)BB * HH * 64;           // 1048576
    const size_t OFF_VBAR = OFF_PAIR + 2 * (size_t)EE;                // 2097152
    // phase-2 extent ≈3.7M floats << 8.4M union; total ws ≈ 85 MB

    ushort* q16   = (ushort*)(ws + OFF_Q);
    ushort* k16   = (ushort*)(ws + OFF_K);
    ushort* v16   = (ushort*)(ws + OFF_V);
    float* sumsq  = ws + OFF_SS;
    int*   deg    = (int*)(ws + OFF_DEG);
    int*   cursor = (int*)(ws + OFF_CUR);
    ushort* WT    = (ushort*)(ws + OFF_WT);
    int*   offs   = (int*)(ws + OFF_OFFS);
    ushort* xq16  = (ushort*)(ws + OFF_XQ16);
    ushort* xs16  = (ushort*)(ws + OFF_XS16);
    ushort* kv16  = (ushort*)(ws + OFF_KV16);
    float* ksum_f = ws + OFF_KSF;
    float* vsum_f = ws + OFF_VSF;
    int2*  pairb  = (int2*)(ws + OFF_PAIR);
    float* vbar   = ws + OFF_VBAR;

    // zero sumsq + deg + cursor (contiguous)
    hipMemsetAsync(sumsq, 0, (16 + 2 * NN) * sizeof(float), stream);
    prep_kernel<<<11008, 256, 0, stream>>>(Wq, Wk, Wv, WT, ei, deg, Xq, Xs, xq16, xs16);
    qkv_scan<<<1537, 256, 0, stream>>>(
        xq16, xs16, WT, bq, bk, bv, q16, k16, v16, sumsq, deg, offs);
    kv_vbar_bucket<<<4352, 256, 0, stream>>>(
        k16, v16, kv16, ksum_f, vsum_f, vbar, ei, ew, deg, offs, cursor, pairb);
    attn_mfma<<<dim3(MM / 64, BB), 256, 0, stream>>>(
        q16, kv16, ksum_f, vsum_f, sumsq, n_nodes, out);
    gcn_gather<<<(NN * 32) / 256, 256, 0, stream>>>(offs, pairb, vbar, out);
}

// Round 7
// 247.959 us; speedup vs baseline: 1.1948x; 1.0093x over previous
//
#include <hip/hip_runtime.h>
#include <hip/hip_bf16.h>

#define NN 32768   // nodes
#define BB 64      // graphs
#define MM 512     // nodes per graph
#define HH 4       // heads
#define DD 64      // head dim
#define INF 256    // input features
#define HD 256     // H*D
#define EE 524288  // edges
#define XSZ 8388608  // NN*INF elements per X matrix

typedef unsigned short ushort;
typedef unsigned int uint;
typedef short s16x8 __attribute__((ext_vector_type(8)));
typedef ushort u16x8 __attribute__((ext_vector_type(8)));
typedef float f32x4 __attribute__((ext_vector_type(4)));

__device__ __forceinline__ ushort f2bf(float f) {
    uint u = __float_as_uint(f);
    return (ushort)((u + 0x7fffu + ((u >> 16) & 1u)) >> 16);
}
__device__ __forceinline__ float bf2f(ushort u) {
    return __uint_as_float((uint)u << 16);
}
__device__ __forceinline__ uint pkbf(float x, float y) {
    __hip_bfloat162 h = __float22bfloat162_rn(make_float2(x, y));
    return *(uint*)&h;
}

#define GLD16(gp, lp) __builtin_amdgcn_global_load_lds( \
    (const __attribute__((address_space(1))) void*)(gp), \
    (__attribute__((address_space(3))) void*)(lp), 16, 0, 0)

// ---------------------------------------------------------------------------
// K1: convert_w (blocks 0..767) ∪ deg histogram (blocks 768..2815) ∪
//     X f32->bf16 convert (blocks 2816..11007).
// ---------------------------------------------------------------------------
__global__ __launch_bounds__(256) void prep_kernel(
    const float* __restrict__ Wq, const float* __restrict__ Wk,
    const float* __restrict__ Wv, ushort* __restrict__ WT,
    const int* __restrict__ ei, int* __restrict__ deg,
    const float* __restrict__ Xq, const float* __restrict__ Xs,
    ushort* __restrict__ xq16, ushort* __restrict__ xs16)
{
    const int bid = blockIdx.x;
    if (bid < 768) {
        const int id = bid * 256 + threadIdx.x;      // 3*65536
        const int mat = id >> 16, rem = id & 65535;
        const int n = rem >> 8, kk = rem & 255;
        const float* W = (mat == 0) ? Wq : (mat == 1) ? Wk : Wv;
        WT[id] = f2bf(W[kk * 256 + n]);              // WT[mat][n][kk]
    } else if (bid < 2816) {
        const int e = (bid - 768) * 256 + threadIdx.x;   // EE total
        atomicAdd(&deg[ei[EE + e]], 1);
    } else {
        const size_t id = (size_t)(bid - 2816) * 256 + threadIdx.x;
        const size_t o8 = id * 8;                    // 8 floats / thread
        const float* src; ushort* dst; size_t o;
        if (o8 < XSZ) { src = Xq; dst = xq16; o = o8; }
        else          { src = Xs; dst = xs16; o = o8 - XSZ; }
        const float4 f0 = *(const float4*)(src + o);
        const float4 f1 = *(const float4*)(src + o + 4);
        u16x8 r;
        r[0] = f2bf(f0.x); r[1] = f2bf(f0.y); r[2] = f2bf(f0.z); r[3] = f2bf(f0.w);
        r[4] = f2bf(f1.x); r[5] = f2bf(f1.y); r[6] = f2bf(f1.z); r[7] = f2bf(f1.w);
        *(u16x8*)(dst + o) = r;
    }
}

// ---------------------------------------------------------------------------
// K2: qkv GEMM (blocks 0..1535) ∪ scan (block 1536).
// T4-pipelined: 3 LDS buffers, counted s_waitcnt vmcnt(4) before raw
// s_barrier, stage issued AFTER the barrier. (round-4, measured 43us)
// ---------------------------------------------------------------------------
__global__ __launch_bounds__(256) void qkv_scan(
    const ushort* __restrict__ Xq16, const ushort* __restrict__ Xs16,
    const ushort* __restrict__ WT,
    const float* __restrict__ bq, const float* __restrict__ bk,
    const float* __restrict__ bv,
    ushort* __restrict__ qo, ushort* __restrict__ ko, ushort* __restrict__ vo,
    float* __restrict__ sumsq,
    const int* __restrict__ deg, int* __restrict__ offsets)
{
    __shared__ ushort As[3][128 * 32];
    __shared__ ushort Bs[3][128 * 32];
    __shared__ float wred[4];
    __shared__ int part[256];

    const int id = blockIdx.x;
    const int t = threadIdx.x;

    if (id == 1536) {   // exclusive scan of deg -> offsets, 128 elems/thread
        const int base = t * 128;
        int s = 0;
        for (int i = 0; i < 128; ++i) s += deg[base + i];
        part[t] = s;
        __syncthreads();
        for (int off = 1; off < 256; off <<= 1) {
            int a = part[t];
            int b2 = (t >= off) ? part[t - off] : 0;
            __syncthreads();
            part[t] = a + b2;
            __syncthreads();
        }
        int run = (t == 0) ? 0 : part[t - 1];
        for (int i = 0; i < 128; ++i) { offsets[base + i] = run; run += deg[base + i]; }
        if (t == 255) offsets[NN] = run;
        return;
    }

    const int vv = (id & 7) * 192 + (id >> 3);   // XCD-contiguous row-groups
    const int rt = vv / 6, ct = vv % 6;
    const int wsel = ct >> 1;                    // 0:q 1:k 2:v
    const ushort* A16 = (wsel == 0) ? Xq16 : Xs16;
    const ushort* W   = WT + (size_t)wsel * 65536;
    const float* bias = (wsel == 0) ? bq : (wsel == 1) ? bk : bv;
    ushort* C         = (wsel == 0) ? qo : (wsel == 1) ? ko : vo;
    const int row0 = rt * 128;
    const int col0 = (ct & 1) * 128;

    const int l = t & 63, w = t >> 6;
    const int fr = l & 15, q4 = l >> 4;
    const int wr = (w & 1) * 64, wc = (w >> 1) * 64;

    // staging: per wave, 64 lanes x 16B contiguous LDS
    const int srow = (w << 4) + (l >> 2);        // 0..63 within 64-row half
    const int scol = (l & 3) << 3;               // 0,8,16,24
    const ushort* ga = &A16[(size_t)(row0 + srow) * INF + scol];
    const ushort* gb = &W  [(size_t)(col0 + srow) * INF + scol];
    const int lbase = (w << 9);                  // wave-uniform ushort offset

    f32x4 acc[4][4] = {};

#define QKV_STAGE(bufi, k0) \
    GLD16(ga + (k0),            &As[bufi][lbase]); \
    GLD16(ga + (k0) + 64 * INF, &As[bufi][2048 + lbase]); \
    GLD16(gb + (k0),            &Bs[bufi][lbase]); \
    GLD16(gb + (k0) + 64 * INF, &Bs[bufi][2048 + lbase]);

#define QKV_COMPUTE(bufi) { \
    const int kg = q4 * 8; \
    s16x8 af[4], bfr[4]; \
    _Pragma("unroll") \
    for (int i = 0; i < 4; ++i) \
        af[i] = *(const s16x8*)&As[bufi][(wr + i * 16 + fr) * 32 + kg]; \
    _Pragma("unroll") \
    for (int j = 0; j < 4; ++j) \
        bfr[j] = *(const s16x8*)&Bs[bufi][(wc + j * 16 + fr) * 32 + kg]; \
    _Pragma("unroll") \
    for (int i = 0; i < 4; ++i) \
    _Pragma("unroll") \
        for (int j = 0; j < 4; ++j) \
            acc[i][j] = __builtin_amdgcn_mfma_f32_16x16x32_bf16( \
                af[i], bfr[j], acc[i][j], 0, 0, 0); }

#define WAIT4 asm volatile("s_waitcnt vmcnt(4)" ::: "memory")
#define WAIT0 asm volatile("s_waitcnt vmcnt(0)" ::: "memory")
#define BAR   __builtin_amdgcn_s_barrier()

    // prologue: buffers 0 and 1 in flight
    QKV_STAGE(0, 0)
    QKV_STAGE(1, 32)

    WAIT4; BAR; QKV_STAGE(2,  64) QKV_COMPUTE(0)   // it0
    WAIT4; BAR; QKV_STAGE(0,  96) QKV_COMPUTE(1)   // it1
    WAIT4; BAR; QKV_STAGE(1, 128) QKV_COMPUTE(2)   // it2
    WAIT4; BAR; QKV_STAGE(2, 160) QKV_COMPUTE(0)   // it3
    WAIT4; BAR; QKV_STAGE(0, 192) QKV_COMPUTE(1)   // it4
    WAIT4; BAR; QKV_STAGE(1, 224) QKV_COMPUTE(2)   // it5
    WAIT4; BAR;                   QKV_COMPUTE(0)   // it6
    WAIT0; BAR;                   QKV_COMPUTE(1)   // it7

    float loc = 0.f;
#pragma unroll
    for (int j = 0; j < 4; ++j) {
        const int colg = col0 + wc + j * 16 + fr;
        const float bj = bias[colg];
#pragma unroll
        for (int i = 0; i < 4; ++i) {
            const int rowg = row0 + wr + i * 16 + q4 * 4;
#pragma unroll
            for (int m = 0; m < 4; ++m) {
                float cv = acc[i][j][m] + bj;
                loc += cv * cv;
                C[(size_t)(rowg + m) * HD + colg] = f2bf(cv);
            }
        }
    }
    if (wsel < 2) {
#pragma unroll
        for (int off = 32; off > 0; off >>= 1) loc += __shfl_down(loc, off, 64);
        if (l == 0) wred[w] = loc;
        __syncthreads();
        if (t == 0) atomicAdd(&sumsq[wsel], wred[0] + wred[1] + wred[2] + wred[3]);
    }
}

// ---------------------------------------------------------------------------
// K3: kv full-pass MFMA (blocks 0..255: one (b,h), 8 chunks of 64 rows,
// in-register accumulation; LDS shrunk to 18.4 KB so the latency-bound
// vbar/bucket sections get 8 blocks/CU) ∪ vbar (blocks 256..1279,
// 16B-vectorized, 8 threads/node) ∪ bucket (blocks 1280..3327).
// ---------------------------------------------------------------------------
#define KVP 72
__global__ __launch_bounds__(256) void kv_vbar_bucket(
    const ushort* __restrict__ k16, const ushort* __restrict__ v16,
    ushort* __restrict__ kv16, float* __restrict__ ksum_f, float* __restrict__ vsum_f,
    float* __restrict__ vbar,
    const int* __restrict__ ei, const float* __restrict__ ew,
    const int* __restrict__ deg, const int* __restrict__ offsets,
    int* __restrict__ cursor, int2* __restrict__ pairbuf)
{
    __shared__ ushort kT[64 * KVP];
    __shared__ ushort vT[64 * KVP];
    const int bid = blockIdx.x;
    const int t = threadIdx.x;

    if (bid >= 1280) {   // bucket: CSR fill, packed int2 {row, val}
        const int e = (bid - 1280) * 256 + t;
        const int row = ei[e], col = ei[EE + e];
        const long long prod = (long long)deg[row] * (long long)deg[col];
        float val = 0.f;
        if (prod > 0) val = ew[e] * __frsqrt_rn((float)prod);
        const int pos = atomicAdd(&cursor[col], 1);
        pairbuf[offsets[col] + pos] = make_int2(row, __float_as_int(val));
        return;
    }
    if (bid >= 256) {    // vbar: mean over heads, 8 d/thread, 16B loads
        const int idx = (bid - 256) * 256 + t;   // NN*8 total
        const int n = idx >> 3, d0 = (idx & 7) * 8;
        const ushort* vr = &v16[(size_t)n * HD + d0];
        u16x8 v0 = *(const u16x8*)(vr);
        u16x8 v1 = *(const u16x8*)(vr + 64);
        u16x8 v2 = *(const u16x8*)(vr + 128);
        u16x8 v3 = *(const u16x8*)(vr + 192);
        float o[8];
#pragma unroll
        for (int j = 0; j < 8; ++j)
            o[j] = 0.25f * (bf2f(v0[j]) + bf2f(v1[j]) + bf2f(v2[j]) + bf2f(v3[j]));
        float* vb = &vbar[(size_t)n * DD + d0];
        *(float4*)(vb)     = make_float4(o[0], o[1], o[2], o[3]);
        *(float4*)(vb + 4) = make_float4(o[4], o[5], o[6], o[7]);
        return;
    }

    // ---- kv MFMA: one (b,h), all 512 rows in 8 chunks of 64 ----
    const int h = bid & 3, b = bid >> 2;
    const int l = t & 63, w = t >> 6;
    const size_t base = (size_t)b * MM * HD + (size_t)h * DD;

    const int fr = l & 15, q4 = l >> 4, kg = q4 * 8;
    const int wr2 = (w & 1) * 32, wc2 = (w >> 1) * 32;
    s16x8 ones;
#pragma unroll
    for (int i = 0; i < 8; ++i) ones[i] = (short)0x3F80;

    f32x4 acc[2][2] = {};
    f32x4 aks[2] = {};
    f32x4 avs[2] = {};

    // staging decomposition (constant across chunks):
    // mat (K/V) x d-quarter (16 d) x row-pair (2 rows) per thread
    const int mat = t >> 7;
    const int rem = t & 127;
    const int dq  = rem >> 5;          // 0..3
    const int u   = rem & 31;          // row-pair index
    const int r0  = 2 * u;             // rows r0, r0+1 within chunk
    const int d0  = dq * 16;
    const ushort* src = mat ? v16 : k16;
    ushort* dst = mat ? vT : kT;

    for (int chunk = 0; chunk < 8; ++chunk) {
        const int m0 = chunk * 64;
        {   // transpose-stage 64 rows x 64 d (2 rows/thread, packed uint)
            const ushort* p0 = &src[base + (size_t)(m0 + r0) * HD + d0];
            const ushort* p1 = p0 + HD;
            u16x8 ra0 = *(const u16x8*)(p0);
            u16x8 ra1 = *(const u16x8*)(p0 + 8);
            u16x8 rb0 = *(const u16x8*)(p1);
            u16x8 rb1 = *(const u16x8*)(p1 + 8);
#pragma unroll
            for (int jj = 0; jj < 8; ++jj) {
                uint pk = (uint)ra0[jj] | ((uint)rb0[jj] << 16);
                *(uint*)&dst[(d0 + jj) * KVP + r0] = pk;
            }
#pragma unroll
            for (int jj = 0; jj < 8; ++jj) {
                uint pk = (uint)ra1[jj] | ((uint)rb1[jj] << 16);
                *(uint*)&dst[(d0 + 8 + jj) * KVP + r0] = pk;
            }
        }
        __syncthreads();

#pragma unroll
        for (int s = 0; s < 2; ++s) {
            const int mo = s * 32 + kg;
            s16x8 af[2], bf[2];
            af[0] = *(const s16x8*)&kT[(wr2 + fr) * KVP + mo];
            af[1] = *(const s16x8*)&kT[(wr2 + 16 + fr) * KVP + mo];
            bf[0] = *(const s16x8*)&vT[(wc2 + fr) * KVP + mo];
            bf[1] = *(const s16x8*)&vT[(wc2 + 16 + fr) * KVP + mo];
#pragma unroll
            for (int il = 0; il < 2; ++il)
#pragma unroll
                for (int jl = 0; jl < 2; ++jl)
                    acc[il][jl] = __builtin_amdgcn_mfma_f32_16x16x32_bf16(
                        af[il], bf[jl], acc[il][jl], 0, 0, 0);
#pragma unroll
            for (int il = 0; il < 2; ++il)
                aks[il] = __builtin_amdgcn_mfma_f32_16x16x32_bf16(
                    af[il], ones, aks[il], 0, 0, 0);
#pragma unroll
            for (int jl = 0; jl < 2; ++jl)
                avs[jl] = __builtin_amdgcn_mfma_f32_16x16x32_bf16(
                    ones, bf[jl], avs[jl], 0, 0, 0);
        }
        __syncthreads();   // protect LDS overwrite by next chunk
    }

    // epilogue: kv16 bf16 direct, transposed [dv][dk]
    ushort* kvb = &kv16[((size_t)b * HH + h) * 4096];
#pragma unroll
    for (int jl = 0; jl < 2; ++jl) {
        const int dv = wc2 + 16 * jl + fr;
#pragma unroll
        for (int il = 0; il < 2; ++il) {
            const int dk = wr2 + 16 * il + q4 * 4;
            uint2 pk = make_uint2(pkbf(acc[il][jl][0], acc[il][jl][1]),
                                  pkbf(acc[il][jl][2], acc[il][jl][3]));
            *(uint2*)&kvb[(size_t)dv * 64 + dk] = pk;
        }
    }
    float* ksb = &ksum_f[((size_t)b * HH + h) * 64];
    float* vsb = &vsum_f[((size_t)b * HH + h) * 64];
    if (wc2 == 0 && fr == 0) {
#pragma unroll
        for (int il = 0; il < 2; ++il)
#pragma unroll
            for (int m = 0; m < 4; ++m)
                ksb[wr2 + 16 * il + q4 * 4 + m] = aks[il][m];
    }
    if (wr2 == 0 && l < 16) {
        vsb[wc2 + l]      = avs[0][0];
        vsb[wc2 + 16 + l] = avs[1][0];
    }
}

// ---------------------------------------------------------------------------
// K5: attn via MFMA. All 4 heads' KV + sums staged once; all 256
// denominators in one phase; head loop pure MFMA+epilogue, 2 barriers.
// ---------------------------------------------------------------------------
#define AKP 72
__global__ __launch_bounds__(256) void attn_mfma(
    const ushort* __restrict__ q16, const ushort* __restrict__ kv16,
    const float* __restrict__ ksum_f, const float* __restrict__ vsum_f,
    const float* __restrict__ sumsq,
    const int* __restrict__ n_nodes, float* __restrict__ out)
{
    const int b = blockIdx.y;
    const int m0 = blockIdx.x * 64;
    const int t = threadIdx.x;
    const int l = t & 63, w = t >> 6;
    const int fr = l & 15, q4 = l >> 4;
    const int wn = (w & 1) * 32, wd = (w >> 1) * 32;

    __shared__ ushort kvbf[HH][64 * AKP];
    __shared__ float ksum_l[HH][64], vsum_l[HH][64], denom_l[HH][64];

    const float nn = (float)n_nodes[b];
    const float inv = 1.0f / (sqrtf(sumsq[0]) * sqrtf(sumsq[1]));

    {   // stage all heads: bf16 KV [dv][dk] + ksum/vsum
        const int dv = t >> 2, dk0 = (t & 3) * 16;
#pragma unroll
        for (int h = 0; h < HH; ++h) {
            const ushort* kvg = &kv16[((size_t)(b * HH + h)) * 4096 + dv * 64 + dk0];
            *(uint4*)&kvbf[h][dv * AKP + dk0]     = *(const uint4*)kvg;
            *(uint4*)&kvbf[h][dv * AKP + dk0 + 8] = *(const uint4*)(kvg + 8);
        }
        const int hh = t >> 6, dd = t & 63;
        ksum_l[hh][dd] = ksum_f[((size_t)(b * HH + hh)) * 64 + dd];
        vsum_l[hh][dd] = vsum_f[((size_t)(b * HH + hh)) * 64 + dd];
    }
    __syncthreads();

    {   // denominators, all heads at once: thread = (row r, head hh)
        const int r = t & 63, hh = t >> 6;
        const ushort* qr = &q16[((size_t)(b * MM + m0 + r)) * HD + hh * DD];
        float dsum = 0.f;
#pragma unroll
        for (int c = 0; c < 8; ++c) {
            u16x8 qv = *(const u16x8*)(qr + 8 * c);
#pragma unroll
            for (int j2 = 0; j2 < 8; ++j2)
                dsum += bf2f(qv[j2]) * ksum_l[hh][8 * c + j2];
        }
        denom_l[hh][r] = nn + inv * dsum;
    }
    __syncthreads();

    f32x4 acco[2][2] = {};
#pragma unroll
    for (int h = 0; h < HH; ++h) {
        f32x4 pacc[2][2] = {};
#pragma unroll
        for (int kx = 0; kx < 2; ++kx) {
            const int k0 = kx * 32;
            s16x8 af[2], bfr[2];
#pragma unroll
            for (int il = 0; il < 2; ++il)
                af[il] = *(const s16x8*)&q16[
                    ((size_t)(b * MM + m0 + wn + 16 * il + fr)) * HD + h * DD + k0 + q4 * 8];
#pragma unroll
            for (int jl = 0; jl < 2; ++jl)
                bfr[jl] = *(const s16x8*)&kvbf[h][(wd + 16 * jl + fr) * AKP + k0 + q4 * 8];
#pragma unroll
            for (int il = 0; il < 2; ++il)
#pragma unroll
                for (int jl = 0; jl < 2; ++jl)
                    pacc[il][jl] = __builtin_amdgcn_mfma_f32_16x16x32_bf16(
                        af[il], bfr[jl], pacc[il][jl], 0, 0, 0);
        }
#pragma unroll
        for (int il = 0; il < 2; ++il)
#pragma unroll
            for (int m = 0; m < 4; ++m) {
                const float rden = 0.25f / denom_l[h][wn + 16 * il + q4 * 4 + m];
#pragma unroll
                for (int jl = 0; jl < 2; ++jl) {
                    const int d = wd + 16 * jl + fr;
                    acco[il][jl][m] += (inv * pacc[il][jl][m] + vsum_l[h][d]) * rden;
                }
            }
    }

#pragma unroll
    for (int il = 0; il < 2; ++il)
#pragma unroll
        for (int m = 0; m < 4; ++m) {
            const size_t node = (size_t)b * MM + m0 + wn + 16 * il + q4 * 4 + m;
#pragma unroll
            for (int jl = 0; jl < 2; ++jl)
                out[node * DD + wd + 16 * jl + fr] = acco[il][jl][m];
        }
}

// ---------------------------------------------------------------------------
// K6: GCN gather, 32 threads/node (2 groups of 16 split even/odd edges,
// combine via shfl_xor 16).
// ---------------------------------------------------------------------------
__global__ __launch_bounds__(256) void gcn_gather(
    const int* __restrict__ offsets, const int2* __restrict__ pairbuf,
    const float* __restrict__ vbar, float* __restrict__ out)
{
    const int t = blockIdx.x * 256 + threadIdx.x;   // NN*32 threads
    const int n = t >> 5;
    const int g = t & 31;
    const int d4 = (g & 15) << 2;
    const int grp = g >> 4;
    const int s = offsets[n], e = offsets[n + 1];
    float ax = 0.f, ay = 0.f, az = 0.f, aw = 0.f;
    int i = s + grp;
    for (; i + 2 < e; i += 4) {   // two edges (stride-2 within group)
        const int2 p0 = pairbuf[i], p1 = pairbuf[i + 2];
        const float w0 = __int_as_float(p0.y), w1 = __int_as_float(p1.y);
        const float4 v0 = *(const float4*)&vbar[(size_t)p0.x * DD + d4];
        const float4 v1 = *(const float4*)&vbar[(size_t)p1.x * DD + d4];
        ax += w0 * v0.x + w1 * v1.x;
        ay += w0 * v0.y + w1 * v1.y;
        az += w0 * v0.z + w1 * v1.z;
        aw += w0 * v0.w + w1 * v1.w;
    }
    if (i < e) {
        const int2 p = pairbuf[i];
        const float wv = __int_as_float(p.y);
        const float4 v = *(const float4*)&vbar[(size_t)p.x * DD + d4];
        ax += wv * v.x; ay += wv * v.y; az += wv * v.z; aw += wv * v.w;
    }
    ax += __shfl_xor(ax, 16, 64);
    ay += __shfl_xor(ay, 16, 64);
    az += __shfl_xor(az, 16, 64);
    aw += __shfl_xor(aw, 16, 64);
    if (grp == 0) {
        float4 o = *(float4*)&out[(size_t)n * DD + d4];
        o.x += ax; o.y += ay; o.z += az; o.w += aw;
        *(float4*)&out[(size_t)n * DD + d4] = o;
    }
}

// ---------------------------------------------------------------------------
extern "C" void kernel_launch(void* const* d_in, const int* in_sizes, int n_in,
                              void* d_out, int out_size, void* d_ws, size_t ws_size,
                              hipStream_t stream)
{
    (void)in_sizes; (void)n_in; (void)out_size; (void)ws_size;
    const float* Xq = (const float*)d_in[0];
    const float* Xs = (const float*)d_in[1];
    const float* ew = (const float*)d_in[2];
    const float* Wq = (const float*)d_in[3];
    const float* bq = (const float*)d_in[4];
    const float* Wk = (const float*)d_in[5];
    const float* bk = (const float*)d_in[6];
    const float* Wv = (const float*)d_in[7];
    const float* bv = (const float*)d_in[8];
    const int* n_nodes = (const int*)d_in[9];
    const int* ei = (const int*)d_in[10];
    float* out = (float*)d_out;
    float* ws  = (float*)d_ws;

    // workspace layout (float units); q/k/v bf16
    const size_t SZ_QKV   = (size_t)NN * HD / 2;       // 4194304 each
    const size_t OFF_Q    = 0;
    const size_t OFF_K    = SZ_QKV;
    const size_t OFF_V    = SZ_QKV * 2;
    const size_t OFF_SS   = SZ_QKV * 3;                // 16 floats (zeroed)
    const size_t OFF_DEG  = OFF_SS + 16;               // NN ints (zeroed)
    const size_t OFF_CUR  = OFF_DEG + NN;              // NN ints (zeroed)
    const size_t OFF_WT   = OFF_CUR + NN;              // 3*65536 ushorts
    const size_t OFF_OFFS = OFF_WT + 3 * 65536 / 2;    // NN+1 (+pad)
    const size_t OFF_UNI  = OFF_OFFS + NN + 16;
    // phase 1 (prep + qkv_scan): Xq16, Xs16 bf16 copies of inputs
    const size_t OFF_XQ16 = OFF_UNI;                   // XSZ/2 = 4194304
    const size_t OFF_XS16 = OFF_UNI + XSZ / 2;         // 4194304
    // phase 2 (kv_vbar_bucket onward) — Xq16/Xs16 dead, region reused:
    const size_t OFF_KV16 = OFF_UNI;                                  // 524288
    const size_t OFF_KSF  = OFF_KV16 + (size_t)BB * HH * 4096 / 2;    // 16384
    const size_t OFF_VSF  = OFF_KSF + (size_t)BB * HH * 64;           // 16384
    const size_t OFF_PAIR = OFF_VSF + (size_t)BB * HH * 64;           // 1048576
    const size_t OFF_VBAR = OFF_PAIR + 2 * (size_t)EE;                // 2097152
    // phase-2 extent ≈3.7M floats << 8.4M union; total ws ≈ 85 MB

    ushort* q16   = (ushort*)(ws + OFF_Q);
    ushort* k16   = (ushort*)(ws + OFF_K);
    ushort* v16   = (ushort*)(ws + OFF_V);
    float* sumsq  = ws + OFF_SS;
    int*   deg    = (int*)(ws + OFF_DEG);
    int*   cursor = (int*)(ws + OFF_CUR);
    ushort* WT    = (ushort*)(ws + OFF_WT);
    int*   offs   = (int*)(ws + OFF_OFFS);
    ushort* xq16  = (ushort*)(ws + OFF_XQ16);
    ushort* xs16  = (ushort*)(ws + OFF_XS16);
    ushort* kv16  = (ushort*)(ws + OFF_KV16);
    float* ksum_f = ws + OFF_KSF;
    float* vsum_f = ws + OFF_VSF;
    int2*  pairb  = (int2*)(ws + OFF_PAIR);
    float* vbar   = ws + OFF_VBAR;

    // zero sumsq + deg + cursor (contiguous)
    hipMemsetAsync(sumsq, 0, (16 + 2 * NN) * sizeof(float), stream);
    prep_kernel<<<11008, 256, 0, stream>>>(Wq, Wk, Wv, WT, ei, deg, Xq, Xs, xq16, xs16);
    qkv_scan<<<1537, 256, 0, stream>>>(
        xq16, xs16, WT, bq, bk, bv, q16, k16, v16, sumsq, deg, offs);
    kv_vbar_bucket<<<3328, 256, 0, stream>>>(
        k16, v16, kv16, ksum_f, vsum_f, vbar, ei, ew, deg, offs, cursor, pairb);
    attn_mfma<<<dim3(MM / 64, BB), 256, 0, stream>>>(
        q16, kv16, ksum_f, vsum_f, sumsq, n_nodes, out);
    gcn_gather<<<(NN * 32) / 256, 256, 0, stream>>>(offs, pairb, vbar, out);
}

// Round 8
// 243.863 us; speedup vs baseline: 1.2149x; 1.0168x over previous
//
#include <hip/hip_runtime.h>
#include <hip/hip_bf16.h>

#define NN 32768   // nodes
#define BB 64      // graphs
#define MM 512     // nodes per graph
#define HH 4       // heads
#define DD 64      // head dim
#define INF 256    // input features
#define HD 256     // H*D
#define EE 524288  // edges

typedef unsigned short ushort;
typedef unsigned int uint;
typedef short s16x8 __attribute__((ext_vector_type(8)));
typedef ushort u16x8 __attribute__((ext_vector_type(8)));
typedef float f32x4 __attribute__((ext_vector_type(4)));

__device__ __forceinline__ ushort f2bf(float f) {
    uint u = __float_as_uint(f);
    return (ushort)((u + 0x7fffu + ((u >> 16) & 1u)) >> 16);
}
__device__ __forceinline__ float bf2f(ushort u) {
    return __uint_as_float((uint)u << 16);
}
__device__ __forceinline__ uint pkbf(float x, float y) {
    __hip_bfloat162 h = __float22bfloat162_rn(make_float2(x, y));
    return *(uint*)&h;
}

#define GLD16(gp, lp) __builtin_amdgcn_global_load_lds( \
    (const __attribute__((address_space(1))) void*)(gp), \
    (__attribute__((address_space(3))) void*)(lp), 16, 0, 0)

// ---------------------------------------------------------------------------
// K1: convert_w (blocks 0..767) ∪ deg histogram (blocks 768..2815).
// X convert removed — qkv converts f32 in-kernel now.
// ---------------------------------------------------------------------------
__global__ __launch_bounds__(256) void prep_kernel(
    const float* __restrict__ Wq, const float* __restrict__ Wk,
    const float* __restrict__ Wv, ushort* __restrict__ WT,
    const int* __restrict__ ei, int* __restrict__ deg)
{
    const int bid = blockIdx.x;
    if (bid < 768) {
        const int id = bid * 256 + threadIdx.x;      // 3*65536
        const int mat = id >> 16, rem = id & 65535;
        const int n = rem >> 8, kk = rem & 255;
        const float* W = (mat == 0) ? Wq : (mat == 1) ? Wk : Wv;
        WT[id] = f2bf(W[kk * 256 + n]);              // WT[mat][n][kk]
    } else {
        const int e = (bid - 768) * 256 + threadIdx.x;   // EE total
        atomicAdd(&deg[ei[EE + e]], 1);
    }
}

// ---------------------------------------------------------------------------
// K2: qkv GEMM (blocks 0..1535) ∪ scan (block 1536).
// A: f32 global->reg (issued post-barrier, 1 compute phase of flight) ->
// cvt_pk bf16 -> ds_write_b128 into 2-buffer LDS (T14 async-split).
// B: bf16 global_load_lds, 3-buffer. Counted vmcnt: vmcnt(2) at iter top
// (A regs ready), vmcnt(8) post-issue (B(cur) landed). 1 barrier/iter.
// Eliminates prep's X f32->bf16 pass entirely.
// ---------------------------------------------------------------------------
__global__ __launch_bounds__(256) void qkv_scan(
    const float* __restrict__ Xq, const float* __restrict__ Xs,
    const ushort* __restrict__ WT,
    const float* __restrict__ bq, const float* __restrict__ bk,
    const float* __restrict__ bv,
    ushort* __restrict__ qo, ushort* __restrict__ ko, ushort* __restrict__ vo,
    float* __restrict__ sumsq,
    const int* __restrict__ deg, int* __restrict__ offsets)
{
    __shared__ ushort As[2][128 * 32];
    __shared__ ushort Bs[3][128 * 32];
    __shared__ float wred[4];
    __shared__ int part[256];

    const int id = blockIdx.x;
    const int t = threadIdx.x;

    if (id == 1536) {   // exclusive scan of deg -> offsets, 128 elems/thread
        const int base = t * 128;
        int s = 0;
        for (int i = 0; i < 128; ++i) s += deg[base + i];
        part[t] = s;
        __syncthreads();
        for (int off = 1; off < 256; off <<= 1) {
            int a = part[t];
            int b2 = (t >= off) ? part[t - off] : 0;
            __syncthreads();
            part[t] = a + b2;
            __syncthreads();
        }
        int run = (t == 0) ? 0 : part[t - 1];
        for (int i = 0; i < 128; ++i) { offsets[base + i] = run; run += deg[base + i]; }
        if (t == 255) offsets[NN] = run;
        return;
    }

    const int vv = (id & 7) * 192 + (id >> 3);   // XCD-contiguous row-groups
    const int rt = vv / 6, ct = vv % 6;
    const int wsel = ct >> 1;                    // 0:q 1:k 2:v
    const float* A    = (wsel == 0) ? Xq : Xs;
    const ushort* W   = WT + (size_t)wsel * 65536;
    const float* bias = (wsel == 0) ? bq : (wsel == 1) ? bk : bv;
    ushort* C         = (wsel == 0) ? qo : (wsel == 1) ? ko : vo;
    const int row0 = rt * 128;
    const int col0 = (ct & 1) * 128;

    const int l = t & 63, w = t >> 6;
    const int fr = l & 15, q4 = l >> 4;
    const int wr = (w & 1) * 64, wc = (w >> 1) * 64;

    // staging geometry: per wave, 64 lanes; row = w*16 + l/4, K-chunk (l&3)*8
    const int srow = (w << 4) + (l >> 2);        // 0..63 within 64-row half
    const int scol = (l & 3) << 3;               // 0,8,16,24 (elems)
    const float*  ga = &A[(size_t)(row0 + srow) * INF + scol];
    const ushort* gb = &W[(size_t)(col0 + srow) * INF + scol];
    const int lbase = (w << 9);                  // wave-uniform ushort offset

    f32x4 acc[4][4] = {};
    float4 a00, a01, a10, a11;                   // A f32 staging regs

#define QKV_ALOAD(k0) { \
    const float* p0 = ga + (k0); \
    const float* p1 = ga + (k0) + 64 * INF; \
    a00 = *(const float4*)(p0);     a01 = *(const float4*)(p0 + 4); \
    a10 = *(const float4*)(p1);     a11 = *(const float4*)(p1 + 4); }

#define QKV_AWRITE(abuf) { \
    union { u16x8 v; uint u[4]; } c0, c1; \
    c0.u[0] = pkbf(a00.x, a00.y); c0.u[1] = pkbf(a00.z, a00.w); \
    c0.u[2] = pkbf(a01.x, a01.y); c0.u[3] = pkbf(a01.z, a01.w); \
    c1.u[0] = pkbf(a10.x, a10.y); c1.u[1] = pkbf(a10.z, a10.w); \
    c1.u[2] = pkbf(a11.x, a11.y); c1.u[3] = pkbf(a11.z, a11.w); \
    *(u16x8*)&As[abuf][srow * 32 + scol]        = c0.v; \
    *(u16x8*)&As[abuf][2048 + srow * 32 + scol] = c1.v; }

#define QKV_BSTAGE(bbuf, k0) \
    GLD16(gb + (k0),            &Bs[bbuf][lbase]); \
    GLD16(gb + (k0) + 64 * INF, &Bs[bbuf][2048 + lbase]);

#define QKV_COMPUTE(abuf, bbuf) { \
    const int kg = q4 * 8; \
    s16x8 af[4], bfr[4]; \
    _Pragma("unroll") \
    for (int i = 0; i < 4; ++i) \
        af[i] = *(const s16x8*)&As[abuf][(wr + i * 16 + fr) * 32 + kg]; \
    _Pragma("unroll") \
    for (int j = 0; j < 4; ++j) \
        bfr[j] = *(const s16x8*)&Bs[bbuf][(wc + j * 16 + fr) * 32 + kg]; \
    _Pragma("unroll") \
    for (int i = 0; i < 4; ++i) \
    _Pragma("unroll") \
        for (int j = 0; j < 4; ++j) \
            acc[i][j] = __builtin_amdgcn_mfma_f32_16x16x32_bf16( \
                af[i], bfr[j], acc[i][j], 0, 0, 0); }

#define WAITN(n) asm volatile("s_waitcnt vmcnt(" #n ")" ::: "memory")
#define LGKM0   asm volatile("s_waitcnt lgkmcnt(0)" ::: "memory")
#define BAR     __builtin_amdgcn_s_barrier()

    // prologue: A(0) regs + B(0), B(1) in flight   [outstanding: A0x4,B0x2,B1x2]
    QKV_ALOAD(0)
    QKV_BSTAGE(0, 0)
    QKV_BSTAGE(1, 32)

    // it0
    WAITN(4); QKV_AWRITE(0) LGKM0; BAR;
    QKV_ALOAD(32)  QKV_BSTAGE(2, 64)   WAITN(8); QKV_COMPUTE(0, 0)
    // it1
    WAITN(2); QKV_AWRITE(1) LGKM0; BAR;
    QKV_ALOAD(64)  QKV_BSTAGE(0, 96)   WAITN(8); QKV_COMPUTE(1, 1)
    // it2
    WAITN(2); QKV_AWRITE(0) LGKM0; BAR;
    QKV_ALOAD(96)  QKV_BSTAGE(1, 128)  WAITN(8); QKV_COMPUTE(0, 2)
    // it3
    WAITN(2); QKV_AWRITE(1) LGKM0; BAR;
    QKV_ALOAD(128) QKV_BSTAGE(2, 160)  WAITN(8); QKV_COMPUTE(1, 0)
    // it4
    WAITN(2); QKV_AWRITE(0) LGKM0; BAR;
    QKV_ALOAD(160) QKV_BSTAGE(0, 192)  WAITN(8); QKV_COMPUTE(0, 1)
    // it5
    WAITN(2); QKV_AWRITE(1) LGKM0; BAR;
    QKV_ALOAD(192) QKV_BSTAGE(1, 224)  WAITN(8); QKV_COMPUTE(1, 2)
    // it6 (no more B to stage)
    WAITN(2); QKV_AWRITE(0) LGKM0; BAR;
    QKV_ALOAD(224)                     WAITN(6); QKV_COMPUTE(0, 0)
    // it7
    WAITN(0); QKV_AWRITE(1) LGKM0; BAR;
    QKV_COMPUTE(1, 1)

    float loc = 0.f;
#pragma unroll
    for (int j = 0; j < 4; ++j) {
        const int colg = col0 + wc + j * 16 + fr;
        const float bj = bias[colg];
#pragma unroll
        for (int i = 0; i < 4; ++i) {
            const int rowg = row0 + wr + i * 16 + q4 * 4;
            const float cv0 = acc[i][j][0] + bj;
            const float cv1 = acc[i][j][1] + bj;
            const float cv2 = acc[i][j][2] + bj;
            const float cv3 = acc[i][j][3] + bj;
            loc += cv0 * cv0 + cv1 * cv1 + cv2 * cv2 + cv3 * cv3;
            const uint p01 = pkbf(cv0, cv1);
            const uint p23 = pkbf(cv2, cv3);
            C[(size_t)(rowg + 0) * HD + colg] = (ushort)p01;
            C[(size_t)(rowg + 1) * HD + colg] = (ushort)(p01 >> 16);
            C[(size_t)(rowg + 2) * HD + colg] = (ushort)p23;
            C[(size_t)(rowg + 3) * HD + colg] = (ushort)(p23 >> 16);
        }
    }
    if (wsel < 2) {
#pragma unroll
        for (int off = 32; off > 0; off >>= 1) loc += __shfl_down(loc, off, 64);
        if (l == 0) wred[w] = loc;
        __syncthreads();
        if (t == 0) atomicAdd(&sumsq[wsel], wred[0] + wred[1] + wred[2] + wred[3]);
    }
}

// ---------------------------------------------------------------------------
// K3: kv full-pass MFMA (blocks 0..255: one (b,h), 8 chunks of 64 rows,
// in-register accumulation; 18.4 KB LDS -> 8 blocks/CU for the
// latency-bound sections) ∪ vbar (blocks 256..1279, 16B loads) ∪
// bucket (blocks 1280..3327).
// ---------------------------------------------------------------------------
#define KVP 72
__global__ __launch_bounds__(256) void kv_vbar_bucket(
    const ushort* __restrict__ k16, const ushort* __restrict__ v16,
    ushort* __restrict__ kv16, float* __restrict__ ksum_f, float* __restrict__ vsum_f,
    float* __restrict__ vbar,
    const int* __restrict__ ei, const float* __restrict__ ew,
    const int* __restrict__ deg, const int* __restrict__ offsets,
    int* __restrict__ cursor, int2* __restrict__ pairbuf)
{
    __shared__ ushort kT[64 * KVP];
    __shared__ ushort vT[64 * KVP];
    const int bid = blockIdx.x;
    const int t = threadIdx.x;

    if (bid >= 1280) {   // bucket: CSR fill, packed int2 {row, val}
        const int e = (bid - 1280) * 256 + t;
        const int row = ei[e], col = ei[EE + e];
        const long long prod = (long long)deg[row] * (long long)deg[col];
        float val = 0.f;
        if (prod > 0) val = ew[e] * __frsqrt_rn((float)prod);
        const int pos = atomicAdd(&cursor[col], 1);
        pairbuf[offsets[col] + pos] = make_int2(row, __float_as_int(val));
        return;
    }
    if (bid >= 256) {    // vbar: mean over heads, 8 d/thread, 16B loads
        const int idx = (bid - 256) * 256 + t;   // NN*8 total
        const int n = idx >> 3, d0 = (idx & 7) * 8;
        const ushort* vr = &v16[(size_t)n * HD + d0];
        u16x8 v0 = *(const u16x8*)(vr);
        u16x8 v1 = *(const u16x8*)(vr + 64);
        u16x8 v2 = *(const u16x8*)(vr + 128);
        u16x8 v3 = *(const u16x8*)(vr + 192);
        float o[8];
#pragma unroll
        for (int j = 0; j < 8; ++j)
            o[j] = 0.25f * (bf2f(v0[j]) + bf2f(v1[j]) + bf2f(v2[j]) + bf2f(v3[j]));
        float* vb = &vbar[(size_t)n * DD + d0];
        *(float4*)(vb)     = make_float4(o[0], o[1], o[2], o[3]);
        *(float4*)(vb + 4) = make_float4(o[4], o[5], o[6], o[7]);
        return;
    }

    // ---- kv MFMA: one (b,h), all 512 rows in 8 chunks of 64 ----
    const int h = bid & 3, b = bid >> 2;
    const int l = t & 63, w = t >> 6;
    const size_t base = (size_t)b * MM * HD + (size_t)h * DD;

    const int fr = l & 15, q4 = l >> 4, kg = q4 * 8;
    const int wr2 = (w & 1) * 32, wc2 = (w >> 1) * 32;
    s16x8 ones;
#pragma unroll
    for (int i = 0; i < 8; ++i) ones[i] = (short)0x3F80;

    f32x4 acc[2][2] = {};
    f32x4 aks[2] = {};
    f32x4 avs[2] = {};

    // staging decomposition (constant across chunks)
    const int mat = t >> 7;
    const int rem = t & 127;
    const int dq  = rem >> 5;          // 0..3
    const int u   = rem & 31;          // row-pair index
    const int r0  = 2 * u;             // rows r0, r0+1 within chunk
    const int d0  = dq * 16;
    const ushort* src = mat ? v16 : k16;
    ushort* dst = mat ? vT : kT;

    for (int chunk = 0; chunk < 8; ++chunk) {
        const int m0 = chunk * 64;
        {   // transpose-stage 64 rows x 64 d (2 rows/thread, packed uint)
            const ushort* p0 = &src[base + (size_t)(m0 + r0) * HD + d0];
            const ushort* p1 = p0 + HD;
            u16x8 ra0 = *(const u16x8*)(p0);
            u16x8 ra1 = *(const u16x8*)(p0 + 8);
            u16x8 rb0 = *(const u16x8*)(p1);
            u16x8 rb1 = *(const u16x8*)(p1 + 8);
#pragma unroll
            for (int jj = 0; jj < 8; ++jj) {
                uint pk = (uint)ra0[jj] | ((uint)rb0[jj] << 16);
                *(uint*)&dst[(d0 + jj) * KVP + r0] = pk;
            }
#pragma unroll
            for (int jj = 0; jj < 8; ++jj) {
                uint pk = (uint)ra1[jj] | ((uint)rb1[jj] << 16);
                *(uint*)&dst[(d0 + 8 + jj) * KVP + r0] = pk;
            }
        }
        __syncthreads();

#pragma unroll
        for (int s = 0; s < 2; ++s) {
            const int mo = s * 32 + kg;
            s16x8 af[2], bf[2];
            af[0] = *(const s16x8*)&kT[(wr2 + fr) * KVP + mo];
            af[1] = *(const s16x8*)&kT[(wr2 + 16 + fr) * KVP + mo];
            bf[0] = *(const s16x8*)&vT[(wc2 + fr) * KVP + mo];
            bf[1] = *(const s16x8*)&vT[(wc2 + 16 + fr) * KVP + mo];
#pragma unroll
            for (int il = 0; il < 2; ++il)
#pragma unroll
                for (int jl = 0; jl < 2; ++jl)
                    acc[il][jl] = __builtin_amdgcn_mfma_f32_16x16x32_bf16(
                        af[il], bf[jl], acc[il][jl], 0, 0, 0);
#pragma unroll
            for (int il = 0; il < 2; ++il)
                aks[il] = __builtin_amdgcn_mfma_f32_16x16x32_bf16(
                    af[il], ones, aks[il], 0, 0, 0);
#pragma unroll
            for (int jl = 0; jl < 2; ++jl)
                avs[jl] = __builtin_amdgcn_mfma_f32_16x16x32_bf16(
                    ones, bf[jl], avs[jl], 0, 0, 0);
        }
        __syncthreads();   // protect LDS overwrite by next chunk
    }

    // epilogue: kv16 bf16 direct, transposed [dv][dk]
    ushort* kvb = &kv16[((size_t)b * HH + h) * 4096];
#pragma unroll
    for (int jl = 0; jl < 2; ++jl) {
        const int dv = wc2 + 16 * jl + fr;
#pragma unroll
        for (int il = 0; il < 2; ++il) {
            const int dk = wr2 + 16 * il + q4 * 4;
            uint2 pk = make_uint2(pkbf(acc[il][jl][0], acc[il][jl][1]),
                                  pkbf(acc[il][jl][2], acc[il][jl][3]));
            *(uint2*)&kvb[(size_t)dv * 64 + dk] = pk;
        }
    }
    float* ksb = &ksum_f[((size_t)b * HH + h) * 64];
    float* vsb = &vsum_f[((size_t)b * HH + h) * 64];
    if (wc2 == 0 && fr == 0) {
#pragma unroll
        for (int il = 0; il < 2; ++il)
#pragma unroll
            for (int m = 0; m < 4; ++m)
                ksb[wr2 + 16 * il + q4 * 4 + m] = aks[il][m];
    }
    if (wr2 == 0 && l < 16) {
        vsb[wc2 + l]      = avs[0][0];
        vsb[wc2 + 16 + l] = avs[1][0];
    }
}

// ---------------------------------------------------------------------------
// K5: attn via MFMA. All 4 heads' KV + sums staged once; all 256
// denominators in one phase; head loop pure MFMA+epilogue, 2 barriers.
// ---------------------------------------------------------------------------
#define AKP 72
__global__ __launch_bounds__(256) void attn_mfma(
    const ushort* __restrict__ q16, const ushort* __restrict__ kv16,
    const float* __restrict__ ksum_f, const float* __restrict__ vsum_f,
    const float* __restrict__ sumsq,
    const int* __restrict__ n_nodes, float* __restrict__ out)
{
    const int b = blockIdx.y;
    const int m0 = blockIdx.x * 64;
    const int t = threadIdx.x;
    const int l = t & 63, w = t >> 6;
    const int fr = l & 15, q4 = l >> 4;
    const int wn = (w & 1) * 32, wd = (w >> 1) * 32;

    __shared__ ushort kvbf[HH][64 * AKP];
    __shared__ float ksum_l[HH][64], vsum_l[HH][64], denom_l[HH][64];

    const float nn = (float)n_nodes[b];
    const float inv = 1.0f / (sqrtf(sumsq[0]) * sqrtf(sumsq[1]));

    {   // stage all heads: bf16 KV [dv][dk] + ksum/vsum
        const int dv = t >> 2, dk0 = (t & 3) * 16;
#pragma unroll
        for (int h = 0; h < HH; ++h) {
            const ushort* kvg = &kv16[((size_t)(b * HH + h)) * 4096 + dv * 64 + dk0];
            *(uint4*)&kvbf[h][dv * AKP + dk0]     = *(const uint4*)kvg;
            *(uint4*)&kvbf[h][dv * AKP + dk0 + 8] = *(const uint4*)(kvg + 8);
        }
        const int hh = t >> 6, dd = t & 63;
        ksum_l[hh][dd] = ksum_f[((size_t)(b * HH + hh)) * 64 + dd];
        vsum_l[hh][dd] = vsum_f[((size_t)(b * HH + hh)) * 64 + dd];
    }
    __syncthreads();

    {   // denominators, all heads at once: thread = (row r, head hh)
        const int r = t & 63, hh = t >> 6;
        const ushort* qr = &q16[((size_t)(b * MM + m0 + r)) * HD + hh * DD];
        float dsum = 0.f;
#pragma unroll
        for (int c = 0; c < 8; ++c) {
            u16x8 qv = *(const u16x8*)(qr + 8 * c);
#pragma unroll
            for (int j2 = 0; j2 < 8; ++j2)
                dsum += bf2f(qv[j2]) * ksum_l[hh][8 * c + j2];
        }
        denom_l[hh][r] = nn + inv * dsum;
    }
    __syncthreads();

    f32x4 acco[2][2] = {};
#pragma unroll
    for (int h = 0; h < HH; ++h) {
        f32x4 pacc[2][2] = {};
#pragma unroll
        for (int kx = 0; kx < 2; ++kx) {
            const int k0 = kx * 32;
            s16x8 af[2], bfr[2];
#pragma unroll
            for (int il = 0; il < 2; ++il)
                af[il] = *(const s16x8*)&q16[
                    ((size_t)(b * MM + m0 + wn + 16 * il + fr)) * HD + h * DD + k0 + q4 * 8];
#pragma unroll
            for (int jl = 0; jl < 2; ++jl)
                bfr[jl] = *(const s16x8*)&kvbf[h][(wd + 16 * jl + fr) * AKP + k0 + q4 * 8];
#pragma unroll
            for (int il = 0; il < 2; ++il)
#pragma unroll
                for (int jl = 0; jl < 2; ++jl)
                    pacc[il][jl] = __builtin_amdgcn_mfma_f32_16x16x32_bf16(
                        af[il], bfr[jl], pacc[il][jl], 0, 0, 0);
        }
#pragma unroll
        for (int il = 0; il < 2; ++il)
#pragma unroll
            for (int m = 0; m < 4; ++m) {
                const float rden = 0.25f / denom_l[h][wn + 16 * il + q4 * 4 + m];
#pragma unroll
                for (int jl = 0; jl < 2; ++jl) {
                    const int d = wd + 16 * jl + fr;
                    acco[il][jl][m] += (inv * pacc[il][jl][m] + vsum_l[h][d]) * rden;
                }
            }
    }

#pragma unroll
    for (int il = 0; il < 2; ++il)
#pragma unroll
        for (int m = 0; m < 4; ++m) {
            const size_t node = (size_t)b * MM + m0 + wn + 16 * il + q4 * 4 + m;
#pragma unroll
            for (int jl = 0; jl < 2; ++jl)
                out[node * DD + wd + 16 * jl + fr] = acco[il][jl][m];
        }
}

// ---------------------------------------------------------------------------
// K6: GCN gather, 32 threads/node (2 groups of 16 split even/odd edges,
// combine via shfl_xor 16).
// ---------------------------------------------------------------------------
__global__ __launch_bounds__(256) void gcn_gather(
    const int* __restrict__ offsets, const int2* __restrict__ pairbuf,
    const float* __restrict__ vbar, float* __restrict__ out)
{
    const int t = blockIdx.x * 256 + threadIdx.x;   // NN*32 threads
    const int n = t >> 5;
    const int g = t & 31;
    const int d4 = (g & 15) << 2;
    const int grp = g >> 4;
    const int s = offsets[n], e = offsets[n + 1];
    float ax = 0.f, ay = 0.f, az = 0.f, aw = 0.f;
    int i = s + grp;
    for (; i + 2 < e; i += 4) {   // two edges (stride-2 within group)
        const int2 p0 = pairbuf[i], p1 = pairbuf[i + 2];
        const float w0 = __int_as_float(p0.y), w1 = __int_as_float(p1.y);
        const float4 v0 = *(const float4*)&vbar[(size_t)p0.x * DD + d4];
        const float4 v1 = *(const float4*)&vbar[(size_t)p1.x * DD + d4];
        ax += w0 * v0.x + w1 * v1.x;
        ay += w0 * v0.y + w1 * v1.y;
        az += w0 * v0.z + w1 * v1.z;
        aw += w0 * v0.w + w1 * v1.w;
    }
    if (i < e) {
        const int2 p = pairbuf[i];
        const float wv = __int_as_float(p.y);
        const float4 v = *(const float4*)&vbar[(size_t)p.x * DD + d4];
        ax += wv * v.x; ay += wv * v.y; az += wv * v.z; aw += wv * v.w;
    }
    ax += __shfl_xor(ax, 16, 64);
    ay += __shfl_xor(ay, 16, 64);
    az += __shfl_xor(az, 16, 64);
    aw += __shfl_xor(aw, 16, 64);
    if (grp == 0) {
        float4 o = *(float4*)&out[(size_t)n * DD + d4];
        o.x += ax; o.y += ay; o.z += az; o.w += aw;
        *(float4*)&out[(size_t)n * DD + d4] = o;
    }
}

// ---------------------------------------------------------------------------
extern "C" void kernel_launch(void* const* d_in, const int* in_sizes, int n_in,
                              void* d_out, int out_size, void* d_ws, size_t ws_size,
                              hipStream_t stream)
{
    (void)in_sizes; (void)n_in; (void)out_size; (void)ws_size;
    const float* Xq = (const float*)d_in[0];
    const float* Xs = (const float*)d_in[1];
    const float* ew = (const float*)d_in[2];
    const float* Wq = (const float*)d_in[3];
    const float* bq = (const float*)d_in[4];
    const float* Wk = (const float*)d_in[5];
    const float* bk = (const float*)d_in[6];
    const float* Wv = (const float*)d_in[7];
    const float* bv = (const float*)d_in[8];
    const int* n_nodes = (const int*)d_in[9];
    const int* ei = (const int*)d_in[10];
    float* out = (float*)d_out;
    float* ws  = (float*)d_ws;

    // workspace layout (float units); q/k/v bf16
    const size_t SZ_QKV   = (size_t)NN * HD / 2;       // 4194304 each
    const size_t OFF_Q    = 0;
    const size_t OFF_K    = SZ_QKV;
    const size_t OFF_V    = SZ_QKV * 2;
    const size_t OFF_SS   = SZ_QKV * 3;                // 16 floats (zeroed)
    const size_t OFF_DEG  = OFF_SS + 16;               // NN ints (zeroed)
    const size_t OFF_CUR  = OFF_DEG + NN;              // NN ints (zeroed)
    const size_t OFF_WT   = OFF_CUR + NN;              // 3*65536 ushorts
    const size_t OFF_OFFS = OFF_WT + 3 * 65536 / 2;    // NN+1 (+pad)
    const size_t OFF_KV16 = OFF_OFFS + NN + 16;                       // 524288 bf16
    const size_t OFF_KSF  = OFF_KV16 + (size_t)BB * HH * 4096 / 2;    // 16384
    const size_t OFF_VSF  = OFF_KSF + (size_t)BB * HH * 64;           // 16384
    const size_t OFF_PAIR = OFF_VSF + (size_t)BB * HH * 64;           // 1048576
    const size_t OFF_VBAR = OFF_PAIR + 2 * (size_t)EE;                // 2097152
    // total ≈ 66 MB

    ushort* q16   = (ushort*)(ws + OFF_Q);
    ushort* k16   = (ushort*)(ws + OFF_K);
    ushort* v16   = (ushort*)(ws + OFF_V);
    float* sumsq  = ws + OFF_SS;
    int*   deg    = (int*)(ws + OFF_DEG);
    int*   cursor = (int*)(ws + OFF_CUR);
    ushort* WT    = (ushort*)(ws + OFF_WT);
    int*   offs   = (int*)(ws + OFF_OFFS);
    ushort* kv16  = (ushort*)(ws + OFF_KV16);
    float* ksum_f = ws + OFF_KSF;
    float* vsum_f = ws + OFF_VSF;
    int2*  pairb  = (int2*)(ws + OFF_PAIR);
    float* vbar   = ws + OFF_VBAR;

    // zero sumsq + deg + cursor (contiguous)
    hipMemsetAsync(sumsq, 0, (16 + 2 * NN) * sizeof(float), stream);
    prep_kernel<<<2816, 256, 0, stream>>>(Wq, Wk, Wv, WT, ei, deg);
    qkv_scan<<<1537, 256, 0, stream>>>(
        Xq, Xs, WT, bq, bk, bv, q16, k16, v16, sumsq, deg, offs);
    kv_vbar_bucket<<<3328, 256, 0, stream>>>(
        k16, v16, kv16, ksum_f, vsum_f, vbar, ei, ew, deg, offs, cursor, pairb);
    attn_mfma<<<dim3(MM / 64, BB), 256, 0, stream>>>(
        q16, kv16, ksum_f, vsum_f, sumsq, n_nodes, out);
    gcn_gather<<<(NN * 32) / 256, 256, 0, stream>>>(offs, pairb, vbar, out);
}